// Round 10
// baseline (231.773 us; speedup 1.0000x reference)
//
#include <hip/hip_runtime.h>

// Linear attention (B=8, T=2048, D=512), chunked, bf16 MFMA, fp32 acc.
// R10: z-fused qkvt at BK=32 / 64KB LDS -> 2 blocks/CU (m97-regime implicit
// overlap). 64B-row swizzle: byte ^= (((row>>1)&3)<<4) (slot-exact, 2-way=free).
//   k_pre   : bf16(x) + W^T transposes                          (4352 blocks)
//   k8_qkvt : q | kk+Kt^T+zsum | Vt^T fused per block           (512 blocks, 64KB LDS)
//   k8_mtst : St = exclusive-chunk-prefix(Vt_c Kt_c^T) fused    (256 blocks)
//   k8_y    : G=tril(QK^T)->LDS, den in-block, y=(QSt^T+GVt^T)/den (256 blocks, 160KB LDS)
//   k8_out  : out = y Wp^T (fp32)                               (256 blocks)
// All GEMMs are C = A * B^T with A:[M][K], B:[N][K] row-major bf16.

typedef __attribute__((ext_vector_type(4))) float f32x4;
typedef __attribute__((ext_vector_type(8))) __bf16 bf16x8;
typedef __attribute__((ext_vector_type(8))) unsigned short ushort8;

// ---- ws layout (byte offsets) ----
constexpr size_t OFF_XB  = 0;                  // bf16 [16384][512]
constexpr size_t OFF_WT  = OFF_XB + 16777216;  // bf16 4x [512][512] (WqT,WkT,WvT,WpT)
constexpr size_t OFF_Q   = OFF_WT + 2097152;   // bf16 [16384][512]
constexpr size_t OFF_KK  = OFF_Q  + 16777216;  // bf16 [16384][512]
constexpr size_t OFF_KT  = OFF_KK + 16777216;  // bf16 [512][16384]
constexpr size_t OFF_VT  = OFF_KT + 16777216;  // bf16 [512][16384]
constexpr size_t OFF_MT  = OFF_VT + 16777216;  // bf16 [64][512][512] St (prefixed)
constexpr size_t OFF_Y   = OFF_MT + 33554432;  // bf16 [16384][512]
constexpr size_t OFF_ZP  = OFF_Y  + 16777216;  // f32  [128][512] half-chunk col sums of kk
constexpr size_t WS_NEED = OFF_ZP + 262144;

__device__ __forceinline__ unsigned short bfbits(float f) {
  __bf16 h = (__bf16)f;
  return __builtin_bit_cast(unsigned short, h);
}
__device__ __forceinline__ float bff(unsigned short u) {
  return (float)__builtin_bit_cast(__bf16, u);
}

__device__ __forceinline__ void gload16(const void* g, void* l) {
  __builtin_amdgcn_global_load_lds((const __attribute__((address_space(1))) void*)g,
                                   (__attribute__((address_space(3))) void*)l, 16, 0, 0);
}

// ============ 128B-row stage/frag pair (mtst, y, out) — proven 0-conflict ============
__device__ __forceinline__ void stage_half(const char* gRow0, size_t ld2, int k0b,
                                           char* ldsHalf, int w, int lane) {
#pragma unroll
  for (int i = 0; i < 2; ++i) {
    int L = (w << 10) + (lane << 4) + (i << 13);
    int r = L >> 7;
    int cb = (L & 127) ^ ((r & 7) << 4);
    gload16(gRow0 + (size_t)r * ld2 + k0b + cb, ldsHalf + (w << 10) + (i << 13));
  }
}

__device__ __forceinline__ void stage_q64(const char* gRow0, size_t ld2, int k0b,
                                          char* lds, int tid) {
  int L = tid << 4;
  int r = L >> 7;
  int cb = (L & 127) ^ ((r & 7) << 4);
  gload16(gRow0 + (size_t)r * ld2 + k0b + cb, lds + L);
}

__device__ __forceinline__ const bf16x8* frag_at(const char* halfBase, int rowInHalf,
                                                 int colByte) {
  int lin = (rowInHalf << 7) + colByte;
  lin ^= (rowInHalf & 7) << 4;
  return (const bf16x8*)(halfBase + lin);
}

// ============ 64B-row stage/frag pair (qkvt BK=32 tiles: [128 rows][32 cols]) ============
// Conflict math: 16 lanes read rows r..r+15 at fixed 16B-slot k. slot(r) =
// (4r + sw(r) ^ k) mod 8 with sw(r) = (r>>1)&3 covers each slot exactly 2x -> free.
__device__ __forceinline__ void stage32s(const char* g, size_t ld2, int k0b,
                                         char* lds, int tid) {
  int L = tid << 4;  // 0..8191
  int r = L >> 6;    // row 0..127
  int cb = (L & 63) ^ (((r >> 1) & 3) << 4);
  gload16(g + (size_t)r * ld2 + k0b + cb, lds + L);
}

__device__ __forceinline__ const bf16x8* frag32s(const char* base, int row, int kB) {
  int lin = (row << 6) + (kB ^ (((row >> 1) & 3) << 4));
  return (const bf16x8*)(base + lin);
}

// ======================= 128x256 8-wave 4-phase core (y, out) =======================
#define QUADH(mh, nh)                                                                  \
  _Pragma("unroll") for (int mm = 0; mm < 2; ++mm)                                     \
  _Pragma("unroll") for (int nn = 0; nn < 2; ++nn)                                     \
  _Pragma("unroll") for (int s = 0; s < 2; ++s)                                        \
      acc[(mh)*2 + mm][(nh)*2 + nn] = __builtin_amdgcn_mfma_f32_16x16x32_bf16(         \
          af[(mh)*2 + mm][s], bg[(nh)*2 + nn][s], acc[(mh)*2 + mm][(nh)*2 + nn], 0, 0, 0);

#define PHASE_TAILH(MH, NH)                                      \
  __builtin_amdgcn_s_barrier();                                  \
  asm volatile("s_waitcnt lgkmcnt(0)" ::: "memory");             \
  __builtin_amdgcn_sched_barrier(0);                             \
  __builtin_amdgcn_s_setprio(1);                                 \
  QUADH(MH, NH);                                                 \
  __builtin_amdgcn_s_setprio(0);                                 \
  __builtin_amdgcn_s_barrier();

__device__ __forceinline__ void core8h(const char* Ab, size_t lda2, const char* Bb,
                                       size_t ldb2, int nt, char* sA, char* sB,
                                       f32x4 (&acc)[4][4], int w, int lane) {
  const int wr = w >> 2, wc = w & 3;
  const int fr = lane & 15, foB = (lane >> 4) << 4;
  const int brow = (wc & 1) << 6;
  const char* gB1 = Bb + (size_t)128 * ldb2;
  bf16x8 af[4][2], bg[4][2];

  stage_half(Ab, lda2, 0, sA + 0, w, lane);
  stage_half(Bb, ldb2, 0, sB + 0, w, lane);
  stage_half(gB1, ldb2, 0, sB + 16384, w, lane);
  if (nt > 1) {
    stage_half(Ab, lda2, 128, sA + 16384, w, lane);
    asm volatile("s_waitcnt vmcnt(2)" ::: "memory");
  } else {
    asm volatile("s_waitcnt vmcnt(0)" ::: "memory");
  }
  __builtin_amdgcn_sched_barrier(0);
  __builtin_amdgcn_s_barrier();

  for (int t = 0; t < nt; ++t) {
    const int buf = t & 1;
    const char* cA = sA + buf * 16384;
    const char* cB = sB + buf * 32768 + (wc >> 1) * 16384;
    char* nA = sA + buf * 16384;
    char* nB = sB + (buf ^ 1) * 32768;
    const int kb1 = (t + 1) << 7, kb2 = (t + 2) << 7;
    const bool stB = (t + 1 < nt), stA = (t + 2 < nt);

#pragma unroll
    for (int m = 0; m < 2; ++m)
#pragma unroll
      for (int s = 0; s < 2; ++s)
        af[m][s] = *frag_at(cA, wr * 64 + m * 16 + fr, s * 64 + foB);
#pragma unroll
    for (int n = 0; n < 2; ++n)
#pragma unroll
      for (int s = 0; s < 2; ++s)
        bg[n][s] = *frag_at(cB, brow + n * 16 + fr, s * 64 + foB);
    if (stB) stage_half(Bb, ldb2, kb1, nB + 0, w, lane);
    PHASE_TAILH(0, 0)

#pragma unroll
    for (int m = 2; m < 4; ++m)
#pragma unroll
      for (int s = 0; s < 2; ++s)
        af[m][s] = *frag_at(cA, wr * 64 + m * 16 + fr, s * 64 + foB);
    if (stB) stage_half(gB1, ldb2, kb1, nB + 16384, w, lane);
    PHASE_TAILH(1, 0)

#pragma unroll
    for (int n = 2; n < 4; ++n)
#pragma unroll
      for (int s = 0; s < 2; ++s)
        bg[n][s] = *frag_at(cB, brow + n * 16 + fr, s * 64 + foB);
    if (stA) stage_half(Ab, lda2, kb2, nA, w, lane);
    PHASE_TAILH(0, 1)

    if (t < nt - 1) {
      if (stA) {
        asm volatile("s_waitcnt vmcnt(2)" ::: "memory");
      } else {
        asm volatile("s_waitcnt vmcnt(0)" ::: "memory");
      }
      __builtin_amdgcn_sched_barrier(0);
    }
    PHASE_TAILH(1, 1)
  }
}

// ---- B-only-staging variant: A fixed in LDS (sG, 16 KB per K-tile) ----
__device__ __forceinline__ void core8h_ldsA(const char* sG, const char* Bb, size_t ldb2,
                                            int nt, char* sB, f32x4 (&acc)[4][4],
                                            int w, int lane) {
  const int wr = w >> 2, wc = w & 3;
  const int fr = lane & 15, foB = (lane >> 4) << 4;
  const int brow = (wc & 1) << 6;
  const char* gB1 = Bb + (size_t)128 * ldb2;
  bf16x8 af[4][2], bg[4][2];

  stage_half(Bb, ldb2, 0, sB + 0, w, lane);
  stage_half(gB1, ldb2, 0, sB + 16384, w, lane);
  asm volatile("s_waitcnt vmcnt(0)" ::: "memory");
  __builtin_amdgcn_sched_barrier(0);
  __builtin_amdgcn_s_barrier();

  for (int t = 0; t < nt; ++t) {
    const int buf = t & 1;
    const char* cA = sG + t * 16384;
    const char* cB = sB + buf * 32768 + (wc >> 1) * 16384;
    char* nB = sB + (buf ^ 1) * 32768;
    if (t + 1 < nt) {
      stage_half(Bb, ldb2, (t + 1) << 7, nB + 0, w, lane);
      stage_half(gB1, ldb2, (t + 1) << 7, nB + 16384, w, lane);
    }
#pragma unroll
    for (int m = 0; m < 4; ++m)
#pragma unroll
      for (int s = 0; s < 2; ++s)
        af[m][s] = *frag_at(cA, wr * 64 + m * 16 + fr, s * 64 + foB);
#pragma unroll
    for (int n = 0; n < 4; ++n)
#pragma unroll
      for (int s = 0; s < 2; ++s)
        bg[n][s] = *frag_at(cB, brow + n * 16 + fr, s * 64 + foB);
    __builtin_amdgcn_s_setprio(1);
#pragma unroll
    for (int m = 0; m < 4; ++m)
#pragma unroll
      for (int n = 0; n < 4; ++n)
#pragma unroll
        for (int s = 0; s < 2; ++s)
          acc[m][n] = __builtin_amdgcn_mfma_f32_16x16x32_bf16(af[m][s], bg[n][s],
                                                              acc[m][n], 0, 0, 0);
    __builtin_amdgcn_s_setprio(0);
    if (t + 1 < nt) {
      asm volatile("s_waitcnt vmcnt(0)" ::: "memory");
      __builtin_amdgcn_sched_barrier(0);
      __builtin_amdgcn_s_barrier();
    }
  }
}

#define ACC4_INIT                                    \
  f32x4 acc[4][4];                                   \
  _Pragma("unroll") for (int m_ = 0; m_ < 4; ++m_)   \
  _Pragma("unroll") for (int n_ = 0; n_ < 4; ++n_)   \
      acc[m_][n_] = f32x4{0.f, 0.f, 0.f, 0.f};

#define ACC4_ZERO                                    \
  _Pragma("unroll") for (int m_ = 0; m_ < 4; ++m_)   \
  _Pragma("unroll") for (int n_ = 0; n_ < 4; ++n_)   \
      acc[m_][n_] = f32x4{0.f, 0.f, 0.f, 0.f};

// ---- z-fused qkvt, BK=32, 64KB LDS, 2 blocks/CU ----
// LDS: sA dbuf 2x8K @0; B_z dbuf 2x8K @ 16K + z*16K (total 64K).
// Per K-tile (16 tiles): 4 gload16/thread (t+1), 10 ds_read_b128, 24 MFMA,
// vmcnt(0), barrier. Co-resident block covers the stalls.
__global__ __launch_bounds__(512, 4) void k8_qkvt(const ushort* __restrict__ xb,
                                                  const ushort* __restrict__ wt,
                                                  ushort* __restrict__ qb,
                                                  ushort* __restrict__ kkb,
                                                  ushort* __restrict__ Kt,
                                                  ushort* __restrict__ Vt,
                                                  float* __restrict__ zsumH) {
  extern __shared__ char smem[];
  const int o = blockIdx.x;
  const int wg = (o & 7) * 64 + (o >> 3);  // bijective: 512 % 8 == 0
  const int mt = wg >> 2, ct = wg & 3;
  const int tid = threadIdx.x, w = tid >> 6, lane = tid & 63;
  const int wr = w >> 2, wc = w & 3;
  const int fr = lane & 15, foB = (lane >> 4) << 4, q4 = (lane >> 4) << 2;
  const char* Ab = (const char*)(xb + (size_t)mt * 128 * 512);
  const char* Bz[3];
  Bz[0] = (const char*)(wt + (size_t)ct * 65536);
  Bz[1] = (const char*)(wt + 262144 + (size_t)ct * 65536);
  Bz[2] = (const char*)(wt + 524288 + (size_t)ct * 65536);
  char* sA = smem;
  char* sB0 = smem + 16384;
  char* sB1 = smem + 32768;
  char* sB2 = smem + 49152;

  f32x4 acc[3][4][2];
#pragma unroll
  for (int z = 0; z < 3; ++z)
#pragma unroll
    for (int m = 0; m < 4; ++m)
#pragma unroll
      for (int n = 0; n < 2; ++n) acc[z][m][n] = f32x4{0.f, 0.f, 0.f, 0.f};

  stage32s(Ab, 1024, 0, sA, tid);
  stage32s(Bz[0], 1024, 0, sB0, tid);
  stage32s(Bz[1], 1024, 0, sB1, tid);
  stage32s(Bz[2], 1024, 0, sB2, tid);
  asm volatile("s_waitcnt vmcnt(0)" ::: "memory");
  __builtin_amdgcn_sched_barrier(0);
  __builtin_amdgcn_s_barrier();

  for (int t = 0; t < 16; ++t) {
    const int buf = t & 1;
    const int bo = buf << 13, nbo = (buf ^ 1) << 13;
    if (t + 1 < 16) {  // staging issued first; lands under the MFMA burst
      const int kb = (t + 1) << 6;
      stage32s(Ab, 1024, kb, sA + nbo, tid);
      stage32s(Bz[0], 1024, kb, sB0 + nbo, tid);
      stage32s(Bz[1], 1024, kb, sB1 + nbo, tid);
      stage32s(Bz[2], 1024, kb, sB2 + nbo, tid);
    }
    bf16x8 af[4], bg[3][2];
#pragma unroll
    for (int m = 0; m < 4; ++m)
      af[m] = *frag32s(sA + bo, wr * 64 + m * 16 + fr, foB);
#pragma unroll
    for (int z = 0; z < 3; ++z)
#pragma unroll
      for (int n = 0; n < 2; ++n)
        bg[z][n] = *frag32s((z == 0 ? sB0 : z == 1 ? sB1 : sB2) + bo,
                            wc * 32 + n * 16 + fr, foB);
    __builtin_amdgcn_s_setprio(1);
#pragma unroll
    for (int z = 0; z < 3; ++z)
#pragma unroll
      for (int m = 0; m < 4; ++m)
#pragma unroll
        for (int n = 0; n < 2; ++n)
          acc[z][m][n] = __builtin_amdgcn_mfma_f32_16x16x32_bf16(af[m], bg[z][n],
                                                                 acc[z][m][n], 0, 0, 0);
    __builtin_amdgcn_s_setprio(0);
    if (t + 1 < 16) {
      asm volatile("s_waitcnt vmcnt(0)" ::: "memory");
    }
    __builtin_amdgcn_sched_barrier(0);
    __builtin_amdgcn_s_barrier();
  }

  const size_t row0 = (size_t)mt * 128 + wr * 64;  // t index
  const size_t col0 = (size_t)ct * 128 + wc * 32;  // d index
  // z=0: q = phi(..)
#pragma unroll
  for (int m = 0; m < 4; ++m)
#pragma unroll
    for (int n = 0; n < 2; ++n)
#pragma unroll
      for (int r = 0; r < 4; ++r) {
        float v = acc[0][m][n][r];
        v = v > 0.f ? v + 1.f : __expf(v);
        qb[(row0 + m * 16 + q4 + r) * 512 + col0 + n * 16 + fr] = bfbits(v);
      }
  // z=2: Vt transposed
#pragma unroll
  for (int m = 0; m < 4; ++m)
#pragma unroll
    for (int n = 0; n < 2; ++n) {
      ushort4 ov;
      ov.x = bfbits(acc[2][m][n][0]);
      ov.y = bfbits(acc[2][m][n][1]);
      ov.z = bfbits(acc[2][m][n][2]);
      ov.w = bfbits(acc[2][m][n][3]);
      *(ushort4*)&Vt[(col0 + n * 16 + fr) * 16384 + row0 + m * 16 + q4] = ov;
    }
  // z=1: kk normal + Kt transposed + col sums
  float zs[2] = {0.f, 0.f};
#pragma unroll
  for (int m = 0; m < 4; ++m)
#pragma unroll
    for (int n = 0; n < 2; ++n) {
      float ph[4];
#pragma unroll
      for (int r = 0; r < 4; ++r) {
        float v = acc[1][m][n][r];
        ph[r] = v > 0.f ? v + 1.f : __expf(v);
        kkb[(row0 + m * 16 + q4 + r) * 512 + col0 + n * 16 + fr] = bfbits(ph[r]);
        zs[n] += ph[r];
      }
      ushort4 ov;
      ov.x = bfbits(ph[0]); ov.y = bfbits(ph[1]); ov.z = bfbits(ph[2]); ov.w = bfbits(ph[3]);
      *(ushort4*)&Kt[(col0 + n * 16 + fr) * 16384 + row0 + m * 16 + q4] = ov;
    }
#pragma unroll
  for (int n = 0; n < 2; ++n) {
    zs[n] += __shfl_xor(zs[n], 16, 64);
    zs[n] += __shfl_xor(zs[n], 32, 64);
  }
  float* zbuf = (float*)smem;  // [2 wr][128 cols]; final K-loop barrier protects reuse
  if (lane < 16) {
#pragma unroll
    for (int n = 0; n < 2; ++n) zbuf[wr * 128 + wc * 32 + n * 16 + fr] = zs[n];
  }
  __syncthreads();
  if (tid < 128)
    zsumH[(size_t)mt * 512 + ct * 128 + tid] = zbuf[tid] + zbuf[128 + tid];
}

// ---- St = exclusive chunk prefix of Vt_c Kt_c^T, fused (per-tile chunk loop) ----
__global__ __launch_bounds__(512, 2) void k8_mtst(const ushort* __restrict__ Kt,
                                                  const ushort* __restrict__ Vt,
                                                  ushort* __restrict__ Mt) {
  __shared__ __align__(16) char smem[49152];  // A 2x16K @0, B 2x8K @32768
  const int o = blockIdx.x;
  const int wg = (o & 7) * 32 + (o >> 3);
  const int et = wg >> 6, b = (wg >> 3) & 7, dt = wg & 7;
  const int tid = threadIdx.x, w = tid >> 6, lane = tid & 63;
  const int wr = w >> 2, wc = w & 3, fr = lane & 15;
  const int foB = (lane >> 4) << 4, q4 = (lane >> 4) << 2;
  const char* Ab = (const char*)(Vt + (size_t)et * 128 * 16384 + b * 2048);
  const char* Bb = (const char*)(Kt + (size_t)dt * 64 * 16384 + b * 2048);
  f32x4 acc[4];
#pragma unroll
  for (int m = 0; m < 4; ++m) acc[m] = f32x4{0.f, 0.f, 0.f, 0.f};

  stage_half(Ab, 32768, 0, smem, w, lane);
  stage_q64(Bb, 32768, 0, smem + 32768, tid);
  asm volatile("s_waitcnt vmcnt(0)" ::: "memory");
  __builtin_amdgcn_sched_barrier(0);
  __builtin_amdgcn_s_barrier();

  const int colg = dt * 64 + wc * 16 + fr;
  for (int kk = 0; kk < 32; ++kk) {
    const int c = kk >> 2, buf = kk & 1;
    if ((kk & 3) == 0) {
      ushort* Sc = Mt + (size_t)(b * 8 + c) * 262144 + colg;
#pragma unroll
      for (int m = 0; m < 4; ++m)
#pragma unroll
        for (int r = 0; r < 4; ++r)
          Sc[(size_t)(et * 128 + wr * 64 + m * 16 + q4 + r) * 512] = bfbits(acc[m][r]);
    }
    if (kk + 1 < 32) {
      const int k0b = ((kk + 1) >> 2) * 512 + ((kk + 1) & 3) * 128;
      stage_half(Ab, 32768, k0b, smem + ((buf ^ 1) << 14), w, lane);
      stage_q64(Bb, 32768, k0b, smem + 32768 + ((buf ^ 1) << 13), tid);
    }
    const char* cA = smem + (buf << 14);
    const char* cB = smem + 32768 + (buf << 13);
    bf16x8 af[4][2], bg[2];
#pragma unroll
    for (int s = 0; s < 2; ++s) bg[s] = *frag_at(cB, wc * 16 + fr, s * 64 + foB);
#pragma unroll
    for (int m = 0; m < 4; ++m)
#pragma unroll
      for (int s = 0; s < 2; ++s)
        af[m][s] = *frag_at(cA, wr * 64 + m * 16 + fr, s * 64 + foB);
    __builtin_amdgcn_s_setprio(1);
#pragma unroll
    for (int m = 0; m < 4; ++m)
#pragma unroll
      for (int s = 0; s < 2; ++s)
        acc[m] = __builtin_amdgcn_mfma_f32_16x16x32_bf16(af[m][s], bg[s], acc[m], 0, 0, 0);
    __builtin_amdgcn_s_setprio(0);
    asm volatile("s_waitcnt vmcnt(0)" ::: "memory");
    __builtin_amdgcn_sched_barrier(0);
    __builtin_amdgcn_s_barrier();
  }
}

// ---- y uber-kernel: G(LDS) + den in-block + y = (Q St^T + G Vt^T)/den ----
__global__ __launch_bounds__(512, 2) void k8_y(const ushort* __restrict__ qb,
                                               const ushort* __restrict__ kkb,
                                               const ushort* __restrict__ St,
                                               const ushort* __restrict__ Vt,
                                               const float* __restrict__ zsumH,
                                               ushort* __restrict__ Y) {
  extern __shared__ char smem[];
  const int o = blockIdx.x;
  const int wg = (o & 7) * 32 + (o >> 3);
  const int bc = wg >> 2, rh = (wg >> 1) & 1, ch = wg & 1;
  const int b = bc >> 3, c = bc & 7;
  const int tid = threadIdx.x, w = tid >> 6, lane = tid & 63;
  const int wr = w >> 2, wc = w & 3, fr = lane & 15, q4 = (lane >> 4) << 2;
  char* sA = smem + 65536;
  char* sB = smem + 98304;
  const char* qptr = (const char*)(qb + (size_t)bc * 131072 + (size_t)rh * 65536);

  ACC4_INIT
  core8h(qptr, 1024, (const char*)(kkb + (size_t)bc * 131072), 1024, 8, sA, sB, acc, w, lane);

  float rs[4][4];
#pragma unroll
  for (int m = 0; m < 4; ++m)
#pragma unroll
    for (int r = 0; r < 4; ++r) rs[m][r] = 0.f;
#pragma unroll
  for (int m = 0; m < 4; ++m)
#pragma unroll
    for (int n = 0; n < 4; ++n)
#pragma unroll
      for (int r = 0; r < 4; ++r) {
        int rowL = wr * 64 + m * 16 + q4 + r;
        int col = wc * 64 + n * 16 + fr;
        float v = (col <= rh * 128 + rowL) ? acc[m][n][r] : 0.f;
        rs[m][r] += v;
        int byte = (rowL << 7) + ((col & 63) << 1);
        byte ^= (rowL & 7) << 4;
        *(__bf16*)(smem + (wc << 14) + byte) = (__bf16)v;
      }
#pragma unroll
  for (int m = 0; m < 4; ++m)
#pragma unroll
    for (int r = 0; r < 4; ++r) {
      rs[m][r] += __shfl_xor(rs[m][r], 1, 64);
      rs[m][r] += __shfl_xor(rs[m][r], 2, 64);
      rs[m][r] += __shfl_xor(rs[m][r], 4, 64);
      rs[m][r] += __shfl_xor(rs[m][r], 8, 64);
    }
  float* red = (float*)sA;
  float* zpl = red + 512;
  float* dend = zpl + 512;
  if (fr == 0) {
#pragma unroll
    for (int m = 0; m < 4; ++m)
#pragma unroll
      for (int r = 0; r < 4; ++r) red[wc * 128 + wr * 64 + m * 16 + q4 + r] = rs[m][r];
  }
  {
    float a = 0.f;
    for (int cp = 0; cp < c; ++cp)
      a += zsumH[(size_t)((b * 8 + cp) * 2) * 512 + tid] +
           zsumH[(size_t)((b * 8 + cp) * 2 + 1) * 512 + tid];
    zpl[tid] = a;
  }
  __syncthreads();
  {
    int rl = tid >> 2, quarter = tid & 3;
    int trow = bc * 256 + rh * 128 + rl;
    const ushort* qrow = qb + (size_t)trow * 512 + quarter * 128;
    const float* zq = zpl + quarter * 128;
    float s = 0.f;
    for (int j = 0; j < 128; j += 8) {
      ushort8 qv = *(const ushort8*)&qrow[j];
#pragma unroll
      for (int u = 0; u < 8; ++u) s = fmaf(bff(qv[u]), zq[j + u], s);
    }
    s += __shfl_xor(s, 1, 64);
    s += __shfl_xor(s, 2, 64);
    if (quarter == 0)
      dend[rl] = s + red[rl] + red[128 + rl] + red[256 + rl] + red[384 + rl] + 1e-6f;
  }
  __syncthreads();
  float dinv[4][4];
#pragma unroll
  for (int m = 0; m < 4; ++m)
#pragma unroll
    for (int r = 0; r < 4; ++r) dinv[m][r] = 1.f / dend[wr * 64 + m * 16 + q4 + r];
  __syncthreads();

  ACC4_ZERO
  core8h(qptr, 1024, (const char*)(St + (size_t)bc * 262144 + (size_t)ch * 131072), 1024, 8,
         sA, sB, acc, w, lane);
  core8h_ldsA(smem, (const char*)(Vt + (size_t)ch * 256 * 16384 + (size_t)bc * 256), 32768,
              rh ? 4 : 2, sB, acc, w, lane);

#pragma unroll
  for (int m = 0; m < 4; ++m)
#pragma unroll
    for (int n = 0; n < 4; ++n)
#pragma unroll
      for (int r = 0; r < 4; ++r) {
        size_t row = (size_t)bc * 256 + rh * 128 + wr * 64 + m * 16 + q4 + r;
        size_t col = (size_t)ch * 256 + wc * 64 + n * 16 + fr;
        Y[row * 512 + col] = bfbits(acc[m][n][r] * dinv[m][r]);
      }
}

// ---- out = Y WpT^T (fp32) : 256 blocks, core8h ----
__global__ __launch_bounds__(512, 2) void k8_out(const ushort* __restrict__ Y,
                                                 const ushort* __restrict__ wt,
                                                 float* __restrict__ out) {
  extern __shared__ char smem[];
  const int o = blockIdx.x;
  const int wg = (o & 7) * 32 + (o >> 3);
  const int mt = wg >> 1, ct = wg & 1;
  const int tid = threadIdx.x, w = tid >> 6, lane = tid & 63;
  ACC4_INIT
  core8h((const char*)(Y + (size_t)mt * 65536), 1024,
         (const char*)(wt + 786432 + (size_t)ct * 131072), 1024, 8,
         smem, smem + 32768, acc, w, lane);
  const int wr = w >> 2, wc = w & 3, fr = lane & 15, q4 = (lane >> 4) << 2;
  const size_t row0 = (size_t)mt * 128 + wr * 64;
  const size_t col0 = (size_t)ct * 256 + wc * 64;
#pragma unroll
  for (int m = 0; m < 4; ++m)
#pragma unroll
    for (int n = 0; n < 4; ++n)
#pragma unroll
      for (int r = 0; r < 4; ++r)
        out[(row0 + m * 16 + q4 + r) * 512 + col0 + n * 16 + fr] = acc[m][n][r];
}

// ---- x -> bf16 (4096 blocks) + W -> W^T bf16 (256 blocks) ----
__global__ __launch_bounds__(256) void k_pre(const float* __restrict__ x,
                                             const float* __restrict__ Wq,
                                             const float* __restrict__ Wk,
                                             const float* __restrict__ Wv,
                                             const float* __restrict__ Wp,
                                             ushort* __restrict__ xb,
                                             ushort* __restrict__ wt) {
  __shared__ float tile[64][65];
  if (blockIdx.x < 4096) {
    size_t i = ((size_t)blockIdx.x * 256 + threadIdx.x) * 8;
    float4 f0 = *(const float4*)&x[i], f1 = *(const float4*)&x[i + 4];
    ushort8 ov;
    ov[0] = bfbits(f0.x); ov[1] = bfbits(f0.y); ov[2] = bfbits(f0.z); ov[3] = bfbits(f0.w);
    ov[4] = bfbits(f1.x); ov[5] = bfbits(f1.y); ov[6] = bfbits(f1.z); ov[7] = bfbits(f1.w);
    *(ushort8*)&xb[i] = ov;
  } else {
    const int g = blockIdx.x - 4096;
    const int bz = g >> 6, rem = g & 63, bxw = rem >> 3, byw = rem & 7;
    const float* src = bz == 0 ? Wq : bz == 1 ? Wk : bz == 2 ? Wv : Wp;
    ushort* dst = wt + (size_t)bz * 262144;
    const int d0 = bxw * 64, n0 = byw * 64;
    const int tr = threadIdx.x >> 4, tc = (threadIdx.x & 15) << 2;
#pragma unroll
    for (int it = 0; it < 4; ++it) {
      float4 f = *(const float4*)&src[(size_t)(d0 + it * 16 + tr) * 512 + n0 + tc];
      tile[it * 16 + tr][tc + 0] = f.x;
      tile[it * 16 + tr][tc + 1] = f.y;
      tile[it * 16 + tr][tc + 2] = f.z;
      tile[it * 16 + tr][tc + 3] = f.w;
    }
    __syncthreads();
#pragma unroll
    for (int it = 0; it < 4; ++it) {
      int n = it * 16 + tr;
      ushort4 ov;
      ov.x = bfbits(tile[tc + 0][n]);
      ov.y = bfbits(tile[tc + 1][n]);
      ov.z = bfbits(tile[tc + 2][n]);
      ov.w = bfbits(tile[tc + 3][n]);
      *(ushort4*)&dst[(size_t)(n0 + n) * 512 + d0 + tc] = ov;
    }
  }
}

extern "C" void kernel_launch(void* const* d_in, const int* in_sizes, int n_in,
                              void* d_out, int out_size, void* d_ws, size_t ws_size,
                              hipStream_t stream) {
  const float* x  = (const float*)d_in[0];
  const float* Wq = (const float*)d_in[1];
  const float* Wk = (const float*)d_in[2];
  const float* Wv = (const float*)d_in[3];
  const float* Wp = (const float*)d_in[4];
  float* out = (float*)d_out;
  char* ws8 = (char*)d_ws;
  if (ws_size < WS_NEED) return;

  ushort* xb  = (ushort*)(ws8 + OFF_XB);
  ushort* wt  = (ushort*)(ws8 + OFF_WT);
  ushort* qb  = (ushort*)(ws8 + OFF_Q);
  ushort* kkb = (ushort*)(ws8 + OFF_KK);
  ushort* Kt  = (ushort*)(ws8 + OFF_KT);
  ushort* Vt  = (ushort*)(ws8 + OFF_VT);
  ushort* Mt  = (ushort*)(ws8 + OFF_MT);
  ushort* Y   = (ushort*)(ws8 + OFF_Y);
  float*  zpH = (float*)(ws8 + OFF_ZP);

  constexpr int SMEM_QKVT = 65536, SMEM_H = 98304, SMEM_Y = 163840;
  hipFuncSetAttribute((const void*)k8_qkvt, hipFuncAttributeMaxDynamicSharedMemorySize, SMEM_QKVT);
  hipFuncSetAttribute((const void*)k8_y,    hipFuncAttributeMaxDynamicSharedMemorySize, SMEM_Y);
  hipFuncSetAttribute((const void*)k8_out,  hipFuncAttributeMaxDynamicSharedMemorySize, SMEM_H);

  k_pre<<<4352, 256, 0, stream>>>(x, Wq, Wk, Wv, Wp, xb, wt);
  k8_qkvt<<<512, 512, SMEM_QKVT, stream>>>(xb, wt, qb, kkb, Kt, Vt, zpH);
  k8_mtst<<<256, 512, 0, stream>>>(Kt, Vt, Mt);
  k8_y<<<256, 512, SMEM_Y, stream>>>(qb, kkb, Mt, Vt, zpH, Y);
  k8_out<<<256, 512, SMEM_H, stream>>>(Y, wt, out);
}

// Round 11
// 133.376 us; speedup vs baseline: 1.7377x; 1.7377x over previous
//
#include <hip/hip_runtime.h>

// Linear attention (B=8, T=2048, D=512), chunked, bf16 MFMA, fp32 acc.
// R11: R10's BK=32 / 64KB-LDS z-fused qkvt with launch_bounds(512,2) so the
// register allocator is NOT capped (R10's (512,4) forced 64 VGPR -> spill).
//   k_pre   : bf16(x) + W^T transposes                          (4352 blocks)
//   k8_qkvt : q | kk+Kt^T+zsum | Vt^T fused per block           (512 blocks, 64KB LDS)
//   k8_mtst : St = exclusive-chunk-prefix(Vt_c Kt_c^T) fused    (256 blocks)
//   k8_y    : G=tril(QK^T)->LDS, den in-block, y=(QSt^T+GVt^T)/den (256 blocks, 160KB LDS)
//   k8_out  : out = y Wp^T (fp32)                               (256 blocks)
// All GEMMs are C = A * B^T with A:[M][K], B:[N][K] row-major bf16.

typedef __attribute__((ext_vector_type(4))) float f32x4;
typedef __attribute__((ext_vector_type(8))) __bf16 bf16x8;
typedef __attribute__((ext_vector_type(8))) unsigned short ushort8;

// ---- ws layout (byte offsets) ----
constexpr size_t OFF_XB  = 0;                  // bf16 [16384][512]
constexpr size_t OFF_WT  = OFF_XB + 16777216;  // bf16 4x [512][512] (WqT,WkT,WvT,WpT)
constexpr size_t OFF_Q   = OFF_WT + 2097152;   // bf16 [16384][512]
constexpr size_t OFF_KK  = OFF_Q  + 16777216;  // bf16 [16384][512]
constexpr size_t OFF_KT  = OFF_KK + 16777216;  // bf16 [512][16384]
constexpr size_t OFF_VT  = OFF_KT + 16777216;  // bf16 [512][16384]
constexpr size_t OFF_MT  = OFF_VT + 16777216;  // bf16 [64][512][512] St (prefixed)
constexpr size_t OFF_Y   = OFF_MT + 33554432;  // bf16 [16384][512]
constexpr size_t OFF_ZP  = OFF_Y  + 16777216;  // f32  [128][512] half-chunk col sums of kk
constexpr size_t WS_NEED = OFF_ZP + 262144;

__device__ __forceinline__ unsigned short bfbits(float f) {
  __bf16 h = (__bf16)f;
  return __builtin_bit_cast(unsigned short, h);
}
__device__ __forceinline__ float bff(unsigned short u) {
  return (float)__builtin_bit_cast(__bf16, u);
}

__device__ __forceinline__ void gload16(const void* g, void* l) {
  __builtin_amdgcn_global_load_lds((const __attribute__((address_space(1))) void*)g,
                                   (__attribute__((address_space(3))) void*)l, 16, 0, 0);
}

// ============ 128B-row stage/frag pair (mtst, y, out) — proven 0-conflict ============
__device__ __forceinline__ void stage_half(const char* gRow0, size_t ld2, int k0b,
                                           char* ldsHalf, int w, int lane) {
#pragma unroll
  for (int i = 0; i < 2; ++i) {
    int L = (w << 10) + (lane << 4) + (i << 13);
    int r = L >> 7;
    int cb = (L & 127) ^ ((r & 7) << 4);
    gload16(gRow0 + (size_t)r * ld2 + k0b + cb, ldsHalf + (w << 10) + (i << 13));
  }
}

__device__ __forceinline__ void stage_q64(const char* gRow0, size_t ld2, int k0b,
                                          char* lds, int tid) {
  int L = tid << 4;
  int r = L >> 7;
  int cb = (L & 127) ^ ((r & 7) << 4);
  gload16(gRow0 + (size_t)r * ld2 + k0b + cb, lds + L);
}

__device__ __forceinline__ const bf16x8* frag_at(const char* halfBase, int rowInHalf,
                                                 int colByte) {
  int lin = (rowInHalf << 7) + colByte;
  lin ^= (rowInHalf & 7) << 4;
  return (const bf16x8*)(halfBase + lin);
}

// ============ 64B-row stage/frag pair (qkvt BK=32 tiles: [128 rows][32 cols]) ============
// Conflict math: 16 lanes read rows r..r+15 at fixed 16B-slot k. slot(r) =
// (4r + sw(r) ^ k) mod 8 with sw(r) = (r>>1)&3 covers each slot exactly 2x -> free.
__device__ __forceinline__ void stage32s(const char* g, size_t ld2, int k0b,
                                         char* lds, int tid) {
  int L = tid << 4;  // 0..8191
  int r = L >> 6;    // row 0..127
  int cb = (L & 63) ^ (((r >> 1) & 3) << 4);
  gload16(g + (size_t)r * ld2 + k0b + cb, lds + L);
}

__device__ __forceinline__ const bf16x8* frag32s(const char* base, int row, int kB) {
  int lin = (row << 6) + (kB ^ (((row >> 1) & 3) << 4));
  return (const bf16x8*)(base + lin);
}

// ======================= 128x256 8-wave 4-phase core (y, out) =======================
#define QUADH(mh, nh)                                                                  \
  _Pragma("unroll") for (int mm = 0; mm < 2; ++mm)                                     \
  _Pragma("unroll") for (int nn = 0; nn < 2; ++nn)                                     \
  _Pragma("unroll") for (int s = 0; s < 2; ++s)                                        \
      acc[(mh)*2 + mm][(nh)*2 + nn] = __builtin_amdgcn_mfma_f32_16x16x32_bf16(         \
          af[(mh)*2 + mm][s], bg[(nh)*2 + nn][s], acc[(mh)*2 + mm][(nh)*2 + nn], 0, 0, 0);

#define PHASE_TAILH(MH, NH)                                      \
  __builtin_amdgcn_s_barrier();                                  \
  asm volatile("s_waitcnt lgkmcnt(0)" ::: "memory");             \
  __builtin_amdgcn_sched_barrier(0);                             \
  __builtin_amdgcn_s_setprio(1);                                 \
  QUADH(MH, NH);                                                 \
  __builtin_amdgcn_s_setprio(0);                                 \
  __builtin_amdgcn_s_barrier();

__device__ __forceinline__ void core8h(const char* Ab, size_t lda2, const char* Bb,
                                       size_t ldb2, int nt, char* sA, char* sB,
                                       f32x4 (&acc)[4][4], int w, int lane) {
  const int wr = w >> 2, wc = w & 3;
  const int fr = lane & 15, foB = (lane >> 4) << 4;
  const int brow = (wc & 1) << 6;
  const char* gB1 = Bb + (size_t)128 * ldb2;
  bf16x8 af[4][2], bg[4][2];

  stage_half(Ab, lda2, 0, sA + 0, w, lane);
  stage_half(Bb, ldb2, 0, sB + 0, w, lane);
  stage_half(gB1, ldb2, 0, sB + 16384, w, lane);
  if (nt > 1) {
    stage_half(Ab, lda2, 128, sA + 16384, w, lane);
    asm volatile("s_waitcnt vmcnt(2)" ::: "memory");
  } else {
    asm volatile("s_waitcnt vmcnt(0)" ::: "memory");
  }
  __builtin_amdgcn_sched_barrier(0);
  __builtin_amdgcn_s_barrier();

  for (int t = 0; t < nt; ++t) {
    const int buf = t & 1;
    const char* cA = sA + buf * 16384;
    const char* cB = sB + buf * 32768 + (wc >> 1) * 16384;
    char* nA = sA + buf * 16384;
    char* nB = sB + (buf ^ 1) * 32768;
    const int kb1 = (t + 1) << 7, kb2 = (t + 2) << 7;
    const bool stB = (t + 1 < nt), stA = (t + 2 < nt);

#pragma unroll
    for (int m = 0; m < 2; ++m)
#pragma unroll
      for (int s = 0; s < 2; ++s)
        af[m][s] = *frag_at(cA, wr * 64 + m * 16 + fr, s * 64 + foB);
#pragma unroll
    for (int n = 0; n < 2; ++n)
#pragma unroll
      for (int s = 0; s < 2; ++s)
        bg[n][s] = *frag_at(cB, brow + n * 16 + fr, s * 64 + foB);
    if (stB) stage_half(Bb, ldb2, kb1, nB + 0, w, lane);
    PHASE_TAILH(0, 0)

#pragma unroll
    for (int m = 2; m < 4; ++m)
#pragma unroll
      for (int s = 0; s < 2; ++s)
        af[m][s] = *frag_at(cA, wr * 64 + m * 16 + fr, s * 64 + foB);
    if (stB) stage_half(gB1, ldb2, kb1, nB + 16384, w, lane);
    PHASE_TAILH(1, 0)

#pragma unroll
    for (int n = 2; n < 4; ++n)
#pragma unroll
      for (int s = 0; s < 2; ++s)
        bg[n][s] = *frag_at(cB, brow + n * 16 + fr, s * 64 + foB);
    if (stA) stage_half(Ab, lda2, kb2, nA, w, lane);
    PHASE_TAILH(0, 1)

    if (t < nt - 1) {
      if (stA) {
        asm volatile("s_waitcnt vmcnt(2)" ::: "memory");
      } else {
        asm volatile("s_waitcnt vmcnt(0)" ::: "memory");
      }
      __builtin_amdgcn_sched_barrier(0);
    }
    PHASE_TAILH(1, 1)
  }
}

// ---- B-only-staging variant: A fixed in LDS (sG, 16 KB per K-tile) ----
__device__ __forceinline__ void core8h_ldsA(const char* sG, const char* Bb, size_t ldb2,
                                            int nt, char* sB, f32x4 (&acc)[4][4],
                                            int w, int lane) {
  const int wr = w >> 2, wc = w & 3;
  const int fr = lane & 15, foB = (lane >> 4) << 4;
  const int brow = (wc & 1) << 6;
  const char* gB1 = Bb + (size_t)128 * ldb2;
  bf16x8 af[4][2], bg[4][2];

  stage_half(Bb, ldb2, 0, sB + 0, w, lane);
  stage_half(gB1, ldb2, 0, sB + 16384, w, lane);
  asm volatile("s_waitcnt vmcnt(0)" ::: "memory");
  __builtin_amdgcn_sched_barrier(0);
  __builtin_amdgcn_s_barrier();

  for (int t = 0; t < nt; ++t) {
    const int buf = t & 1;
    const char* cA = sG + t * 16384;
    const char* cB = sB + buf * 32768 + (wc >> 1) * 16384;
    char* nB = sB + (buf ^ 1) * 32768;
    if (t + 1 < nt) {
      stage_half(Bb, ldb2, (t + 1) << 7, nB + 0, w, lane);
      stage_half(gB1, ldb2, (t + 1) << 7, nB + 16384, w, lane);
    }
#pragma unroll
    for (int m = 0; m < 4; ++m)
#pragma unroll
      for (int s = 0; s < 2; ++s)
        af[m][s] = *frag_at(cA, wr * 64 + m * 16 + fr, s * 64 + foB);
#pragma unroll
    for (int n = 0; n < 4; ++n)
#pragma unroll
      for (int s = 0; s < 2; ++s)
        bg[n][s] = *frag_at(cB, brow + n * 16 + fr, s * 64 + foB);
    __builtin_amdgcn_s_setprio(1);
#pragma unroll
    for (int m = 0; m < 4; ++m)
#pragma unroll
      for (int n = 0; n < 4; ++n)
#pragma unroll
        for (int s = 0; s < 2; ++s)
          acc[m][n] = __builtin_amdgcn_mfma_f32_16x16x32_bf16(af[m][s], bg[n][s],
                                                              acc[m][n], 0, 0, 0);
    __builtin_amdgcn_s_setprio(0);
    if (t + 1 < nt) {
      asm volatile("s_waitcnt vmcnt(0)" ::: "memory");
      __builtin_amdgcn_sched_barrier(0);
      __builtin_amdgcn_s_barrier();
    }
  }
}

#define ACC4_INIT                                    \
  f32x4 acc[4][4];                                   \
  _Pragma("unroll") for (int m_ = 0; m_ < 4; ++m_)   \
  _Pragma("unroll") for (int n_ = 0; n_ < 4; ++n_)   \
      acc[m_][n_] = f32x4{0.f, 0.f, 0.f, 0.f};

#define ACC4_ZERO                                    \
  _Pragma("unroll") for (int m_ = 0; m_ < 4; ++m_)   \
  _Pragma("unroll") for (int n_ = 0; n_ < 4; ++n_)   \
      acc[m_][n_] = f32x4{0.f, 0.f, 0.f, 0.f};

// ---- z-fused qkvt, BK=32, 64KB LDS -> 2 blocks/CU (VGPR permitting) ----
// launch_bounds(512,2): do NOT cap the allocator (R10's (512,4) forced
// 64 VGPR and spilled acc to scratch: FETCH 20->152MB, WRITE 68->374MB).
__global__ __launch_bounds__(512, 2) void k8_qkvt(const ushort* __restrict__ xb,
                                                  const ushort* __restrict__ wt,
                                                  ushort* __restrict__ qb,
                                                  ushort* __restrict__ kkb,
                                                  ushort* __restrict__ Kt,
                                                  ushort* __restrict__ Vt,
                                                  float* __restrict__ zsumH) {
  extern __shared__ char smem[];
  const int o = blockIdx.x;
  const int wg = (o & 7) * 64 + (o >> 3);  // bijective: 512 % 8 == 0
  const int mt = wg >> 2, ct = wg & 3;
  const int tid = threadIdx.x, w = tid >> 6, lane = tid & 63;
  const int wr = w >> 2, wc = w & 3;
  const int fr = lane & 15, foB = (lane >> 4) << 4, q4 = (lane >> 4) << 2;
  const char* Ab = (const char*)(xb + (size_t)mt * 128 * 512);
  const char* Bz[3];
  Bz[0] = (const char*)(wt + (size_t)ct * 65536);
  Bz[1] = (const char*)(wt + 262144 + (size_t)ct * 65536);
  Bz[2] = (const char*)(wt + 524288 + (size_t)ct * 65536);
  char* sA = smem;
  char* sB0 = smem + 16384;
  char* sB1 = smem + 32768;
  char* sB2 = smem + 49152;

  f32x4 acc[3][4][2];
#pragma unroll
  for (int z = 0; z < 3; ++z)
#pragma unroll
    for (int m = 0; m < 4; ++m)
#pragma unroll
      for (int n = 0; n < 2; ++n) acc[z][m][n] = f32x4{0.f, 0.f, 0.f, 0.f};

  stage32s(Ab, 1024, 0, sA, tid);
  stage32s(Bz[0], 1024, 0, sB0, tid);
  stage32s(Bz[1], 1024, 0, sB1, tid);
  stage32s(Bz[2], 1024, 0, sB2, tid);
  asm volatile("s_waitcnt vmcnt(0)" ::: "memory");
  __builtin_amdgcn_sched_barrier(0);
  __builtin_amdgcn_s_barrier();

  for (int t = 0; t < 16; ++t) {
    const int buf = t & 1;
    const int bo = buf << 13, nbo = (buf ^ 1) << 13;
    if (t + 1 < 16) {  // staging issued first; lands under the MFMA burst
      const int kb = (t + 1) << 6;
      stage32s(Ab, 1024, kb, sA + nbo, tid);
      stage32s(Bz[0], 1024, kb, sB0 + nbo, tid);
      stage32s(Bz[1], 1024, kb, sB1 + nbo, tid);
      stage32s(Bz[2], 1024, kb, sB2 + nbo, tid);
    }
    bf16x8 af[4], bg[3][2];
#pragma unroll
    for (int m = 0; m < 4; ++m)
      af[m] = *frag32s(sA + bo, wr * 64 + m * 16 + fr, foB);
#pragma unroll
    for (int z = 0; z < 3; ++z)
#pragma unroll
      for (int n = 0; n < 2; ++n)
        bg[z][n] = *frag32s((z == 0 ? sB0 : z == 1 ? sB1 : sB2) + bo,
                            wc * 32 + n * 16 + fr, foB);
    __builtin_amdgcn_s_setprio(1);
#pragma unroll
    for (int z = 0; z < 3; ++z)
#pragma unroll
      for (int m = 0; m < 4; ++m)
#pragma unroll
        for (int n = 0; n < 2; ++n)
          acc[z][m][n] = __builtin_amdgcn_mfma_f32_16x16x32_bf16(af[m], bg[z][n],
                                                                 acc[z][m][n], 0, 0, 0);
    __builtin_amdgcn_s_setprio(0);
    if (t + 1 < 16) {
      asm volatile("s_waitcnt vmcnt(0)" ::: "memory");
    }
    __builtin_amdgcn_sched_barrier(0);
    __builtin_amdgcn_s_barrier();
  }

  const size_t row0 = (size_t)mt * 128 + wr * 64;  // t index
  const size_t col0 = (size_t)ct * 128 + wc * 32;  // d index
  // z=0: q = phi(..)
#pragma unroll
  for (int m = 0; m < 4; ++m)
#pragma unroll
    for (int n = 0; n < 2; ++n)
#pragma unroll
      for (int r = 0; r < 4; ++r) {
        float v = acc[0][m][n][r];
        v = v > 0.f ? v + 1.f : __expf(v);
        qb[(row0 + m * 16 + q4 + r) * 512 + col0 + n * 16 + fr] = bfbits(v);
      }
  // z=2: Vt transposed
#pragma unroll
  for (int m = 0; m < 4; ++m)
#pragma unroll
    for (int n = 0; n < 2; ++n) {
      ushort4 ov;
      ov.x = bfbits(acc[2][m][n][0]);
      ov.y = bfbits(acc[2][m][n][1]);
      ov.z = bfbits(acc[2][m][n][2]);
      ov.w = bfbits(acc[2][m][n][3]);
      *(ushort4*)&Vt[(col0 + n * 16 + fr) * 16384 + row0 + m * 16 + q4] = ov;
    }
  // z=1: kk normal + Kt transposed + col sums
  float zs[2] = {0.f, 0.f};
#pragma unroll
  for (int m = 0; m < 4; ++m)
#pragma unroll
    for (int n = 0; n < 2; ++n) {
      float ph[4];
#pragma unroll
      for (int r = 0; r < 4; ++r) {
        float v = acc[1][m][n][r];
        ph[r] = v > 0.f ? v + 1.f : __expf(v);
        kkb[(row0 + m * 16 + q4 + r) * 512 + col0 + n * 16 + fr] = bfbits(ph[r]);
        zs[n] += ph[r];
      }
      ushort4 ov;
      ov.x = bfbits(ph[0]); ov.y = bfbits(ph[1]); ov.z = bfbits(ph[2]); ov.w = bfbits(ph[3]);
      *(ushort4*)&Kt[(col0 + n * 16 + fr) * 16384 + row0 + m * 16 + q4] = ov;
    }
#pragma unroll
  for (int n = 0; n < 2; ++n) {
    zs[n] += __shfl_xor(zs[n], 16, 64);
    zs[n] += __shfl_xor(zs[n], 32, 64);
  }
  float* zbuf = (float*)smem;  // [2 wr][128 cols]; final K-loop barrier protects reuse
  if (lane < 16) {
#pragma unroll
    for (int n = 0; n < 2; ++n) zbuf[wr * 128 + wc * 32 + n * 16 + fr] = zs[n];
  }
  __syncthreads();
  if (tid < 128)
    zsumH[(size_t)mt * 512 + ct * 128 + tid] = zbuf[tid] + zbuf[128 + tid];
}

// ---- St = exclusive chunk prefix of Vt_c Kt_c^T, fused (per-tile chunk loop) ----
__global__ __launch_bounds__(512, 2) void k8_mtst(const ushort* __restrict__ Kt,
                                                  const ushort* __restrict__ Vt,
                                                  ushort* __restrict__ Mt) {
  __shared__ __align__(16) char smem[49152];  // A 2x16K @0, B 2x8K @32768
  const int o = blockIdx.x;
  const int wg = (o & 7) * 32 + (o >> 3);
  const int et = wg >> 6, b = (wg >> 3) & 7, dt = wg & 7;
  const int tid = threadIdx.x, w = tid >> 6, lane = tid & 63;
  const int wr = w >> 2, wc = w & 3, fr = lane & 15;
  const int foB = (lane >> 4) << 4, q4 = (lane >> 4) << 2;
  const char* Ab = (const char*)(Vt + (size_t)et * 128 * 16384 + b * 2048);
  const char* Bb = (const char*)(Kt + (size_t)dt * 64 * 16384 + b * 2048);
  f32x4 acc[4];
#pragma unroll
  for (int m = 0; m < 4; ++m) acc[m] = f32x4{0.f, 0.f, 0.f, 0.f};

  stage_half(Ab, 32768, 0, smem, w, lane);
  stage_q64(Bb, 32768, 0, smem + 32768, tid);
  asm volatile("s_waitcnt vmcnt(0)" ::: "memory");
  __builtin_amdgcn_sched_barrier(0);
  __builtin_amdgcn_s_barrier();

  const int colg = dt * 64 + wc * 16 + fr;
  for (int kk = 0; kk < 32; ++kk) {
    const int c = kk >> 2, buf = kk & 1;
    if ((kk & 3) == 0) {
      ushort* Sc = Mt + (size_t)(b * 8 + c) * 262144 + colg;
#pragma unroll
      for (int m = 0; m < 4; ++m)
#pragma unroll
        for (int r = 0; r < 4; ++r)
          Sc[(size_t)(et * 128 + wr * 64 + m * 16 + q4 + r) * 512] = bfbits(acc[m][r]);
    }
    if (kk + 1 < 32) {
      const int k0b = ((kk + 1) >> 2) * 512 + ((kk + 1) & 3) * 128;
      stage_half(Ab, 32768, k0b, smem + ((buf ^ 1) << 14), w, lane);
      stage_q64(Bb, 32768, k0b, smem + 32768 + ((buf ^ 1) << 13), tid);
    }
    const char* cA = smem + (buf << 14);
    const char* cB = smem + 32768 + (buf << 13);
    bf16x8 af[4][2], bg[2];
#pragma unroll
    for (int s = 0; s < 2; ++s) bg[s] = *frag_at(cB, wc * 16 + fr, s * 64 + foB);
#pragma unroll
    for (int m = 0; m < 4; ++m)
#pragma unroll
      for (int s = 0; s < 2; ++s)
        af[m][s] = *frag_at(cA, wr * 64 + m * 16 + fr, s * 64 + foB);
    __builtin_amdgcn_s_setprio(1);
#pragma unroll
    for (int m = 0; m < 4; ++m)
#pragma unroll
      for (int s = 0; s < 2; ++s)
        acc[m] = __builtin_amdgcn_mfma_f32_16x16x32_bf16(af[m][s], bg[s], acc[m], 0, 0, 0);
    __builtin_amdgcn_s_setprio(0);
    asm volatile("s_waitcnt vmcnt(0)" ::: "memory");
    __builtin_amdgcn_sched_barrier(0);
    __builtin_amdgcn_s_barrier();
  }
}

// ---- y uber-kernel: G(LDS) + den in-block + y = (Q St^T + G Vt^T)/den ----
__global__ __launch_bounds__(512, 2) void k8_y(const ushort* __restrict__ qb,
                                               const ushort* __restrict__ kkb,
                                               const ushort* __restrict__ St,
                                               const ushort* __restrict__ Vt,
                                               const float* __restrict__ zsumH,
                                               ushort* __restrict__ Y) {
  extern __shared__ char smem[];
  const int o = blockIdx.x;
  const int wg = (o & 7) * 32 + (o >> 3);
  const int bc = wg >> 2, rh = (wg >> 1) & 1, ch = wg & 1;
  const int b = bc >> 3, c = bc & 7;
  const int tid = threadIdx.x, w = tid >> 6, lane = tid & 63;
  const int wr = w >> 2, wc = w & 3, fr = lane & 15, q4 = (lane >> 4) << 2;
  char* sA = smem + 65536;
  char* sB = smem + 98304;
  const char* qptr = (const char*)(qb + (size_t)bc * 131072 + (size_t)rh * 65536);

  ACC4_INIT
  core8h(qptr, 1024, (const char*)(kkb + (size_t)bc * 131072), 1024, 8, sA, sB, acc, w, lane);

  float rs[4][4];
#pragma unroll
  for (int m = 0; m < 4; ++m)
#pragma unroll
    for (int r = 0; r < 4; ++r) rs[m][r] = 0.f;
#pragma unroll
  for (int m = 0; m < 4; ++m)
#pragma unroll
    for (int n = 0; n < 4; ++n)
#pragma unroll
      for (int r = 0; r < 4; ++r) {
        int rowL = wr * 64 + m * 16 + q4 + r;
        int col = wc * 64 + n * 16 + fr;
        float v = (col <= rh * 128 + rowL) ? acc[m][n][r] : 0.f;
        rs[m][r] += v;
        int byte = (rowL << 7) + ((col & 63) << 1);
        byte ^= (rowL & 7) << 4;
        *(__bf16*)(smem + (wc << 14) + byte) = (__bf16)v;
      }
#pragma unroll
  for (int m = 0; m < 4; ++m)
#pragma unroll
    for (int r = 0; r < 4; ++r) {
      rs[m][r] += __shfl_xor(rs[m][r], 1, 64);
      rs[m][r] += __shfl_xor(rs[m][r], 2, 64);
      rs[m][r] += __shfl_xor(rs[m][r], 4, 64);
      rs[m][r] += __shfl_xor(rs[m][r], 8, 64);
    }
  float* red = (float*)sA;
  float* zpl = red + 512;
  float* dend = zpl + 512;
  if (fr == 0) {
#pragma unroll
    for (int m = 0; m < 4; ++m)
#pragma unroll
      for (int r = 0; r < 4; ++r) red[wc * 128 + wr * 64 + m * 16 + q4 + r] = rs[m][r];
  }
  {
    float a = 0.f;
    for (int cp = 0; cp < c; ++cp)
      a += zsumH[(size_t)((b * 8 + cp) * 2) * 512 + tid] +
           zsumH[(size_t)((b * 8 + cp) * 2 + 1) * 512 + tid];
    zpl[tid] = a;
  }
  __syncthreads();
  {
    int rl = tid >> 2, quarter = tid & 3;
    int trow = bc * 256 + rh * 128 + rl;
    const ushort* qrow = qb + (size_t)trow * 512 + quarter * 128;
    const float* zq = zpl + quarter * 128;
    float s = 0.f;
    for (int j = 0; j < 128; j += 8) {
      ushort8 qv = *(const ushort8*)&qrow[j];
#pragma unroll
      for (int u = 0; u < 8; ++u) s = fmaf(bff(qv[u]), zq[j + u], s);
    }
    s += __shfl_xor(s, 1, 64);
    s += __shfl_xor(s, 2, 64);
    if (quarter == 0)
      dend[rl] = s + red[rl] + red[128 + rl] + red[256 + rl] + red[384 + rl] + 1e-6f;
  }
  __syncthreads();
  float dinv[4][4];
#pragma unroll
  for (int m = 0; m < 4; ++m)
#pragma unroll
    for (int r = 0; r < 4; ++r) dinv[m][r] = 1.f / dend[wr * 64 + m * 16 + q4 + r];
  __syncthreads();

  ACC4_ZERO
  core8h(qptr, 1024, (const char*)(St + (size_t)bc * 262144 + (size_t)ch * 131072), 1024, 8,
         sA, sB, acc, w, lane);
  core8h_ldsA(smem, (const char*)(Vt + (size_t)ch * 256 * 16384 + (size_t)bc * 256), 32768,
              rh ? 4 : 2, sB, acc, w, lane);

#pragma unroll
  for (int m = 0; m < 4; ++m)
#pragma unroll
    for (int n = 0; n < 4; ++n)
#pragma unroll
      for (int r = 0; r < 4; ++r) {
        size_t row = (size_t)bc * 256 + rh * 128 + wr * 64 + m * 16 + q4 + r;
        size_t col = (size_t)ch * 256 + wc * 64 + n * 16 + fr;
        Y[row * 512 + col] = bfbits(acc[m][n][r] * dinv[m][r]);
      }
}

// ---- out = Y WpT^T (fp32) : 256 blocks, core8h ----
__global__ __launch_bounds__(512, 2) void k8_out(const ushort* __restrict__ Y,
                                                 const ushort* __restrict__ wt,
                                                 float* __restrict__ out) {
  extern __shared__ char smem[];
  const int o = blockIdx.x;
  const int wg = (o & 7) * 32 + (o >> 3);
  const int mt = wg >> 1, ct = wg & 1;
  const int tid = threadIdx.x, w = tid >> 6, lane = tid & 63;
  ACC4_INIT
  core8h((const char*)(Y + (size_t)mt * 65536), 1024,
         (const char*)(wt + 786432 + (size_t)ct * 131072), 1024, 8,
         smem, smem + 32768, acc, w, lane);
  const int wr = w >> 2, wc = w & 3, fr = lane & 15, q4 = (lane >> 4) << 2;
  const size_t row0 = (size_t)mt * 128 + wr * 64;
  const size_t col0 = (size_t)ct * 256 + wc * 64;
#pragma unroll
  for (int m = 0; m < 4; ++m)
#pragma unroll
    for (int n = 0; n < 4; ++n)
#pragma unroll
      for (int r = 0; r < 4; ++r)
        out[(row0 + m * 16 + q4 + r) * 512 + col0 + n * 16 + fr] = acc[m][n][r];
}

// ---- x -> bf16 (4096 blocks) + W -> W^T bf16 (256 blocks) ----
__global__ __launch_bounds__(256) void k_pre(const float* __restrict__ x,
                                             const float* __restrict__ Wq,
                                             const float* __restrict__ Wk,
                                             const float* __restrict__ Wv,
                                             const float* __restrict__ Wp,
                                             ushort* __restrict__ xb,
                                             ushort* __restrict__ wt) {
  __shared__ float tile[64][65];
  if (blockIdx.x < 4096) {
    size_t i = ((size_t)blockIdx.x * 256 + threadIdx.x) * 8;
    float4 f0 = *(const float4*)&x[i], f1 = *(const float4*)&x[i + 4];
    ushort8 ov;
    ov[0] = bfbits(f0.x); ov[1] = bfbits(f0.y); ov[2] = bfbits(f0.z); ov[3] = bfbits(f0.w);
    ov[4] = bfbits(f1.x); ov[5] = bfbits(f1.y); ov[6] = bfbits(f1.z); ov[7] = bfbits(f1.w);
    *(ushort8*)&xb[i] = ov;
  } else {
    const int g = blockIdx.x - 4096;
    const int bz = g >> 6, rem = g & 63, bxw = rem >> 3, byw = rem & 7;
    const float* src = bz == 0 ? Wq : bz == 1 ? Wk : bz == 2 ? Wv : Wp;
    ushort* dst = wt + (size_t)bz * 262144;
    const int d0 = bxw * 64, n0 = byw * 64;
    const int tr = threadIdx.x >> 4, tc = (threadIdx.x & 15) << 2;
#pragma unroll
    for (int it = 0; it < 4; ++it) {
      float4 f = *(const float4*)&src[(size_t)(d0 + it * 16 + tr) * 512 + n0 + tc];
      tile[it * 16 + tr][tc + 0] = f.x;
      tile[it * 16 + tr][tc + 1] = f.y;
      tile[it * 16 + tr][tc + 2] = f.z;
      tile[it * 16 + tr][tc + 3] = f.w;
    }
    __syncthreads();
#pragma unroll
    for (int it = 0; it < 4; ++it) {
      int n = it * 16 + tr;
      ushort4 ov;
      ov.x = bfbits(tile[tc + 0][n]);
      ov.y = bfbits(tile[tc + 1][n]);
      ov.z = bfbits(tile[tc + 2][n]);
      ov.w = bfbits(tile[tc + 3][n]);
      *(ushort4*)&dst[(size_t)(n0 + n) * 512 + d0 + tc] = ov;
    }
  }
}

extern "C" void kernel_launch(void* const* d_in, const int* in_sizes, int n_in,
                              void* d_out, int out_size, void* d_ws, size_t ws_size,
                              hipStream_t stream) {
  const float* x  = (const float*)d_in[0];
  const float* Wq = (const float*)d_in[1];
  const float* Wk = (const float*)d_in[2];
  const float* Wv = (const float*)d_in[3];
  const float* Wp = (const float*)d_in[4];
  float* out = (float*)d_out;
  char* ws8 = (char*)d_ws;
  if (ws_size < WS_NEED) return;

  ushort* xb  = (ushort*)(ws8 + OFF_XB);
  ushort* wt  = (ushort*)(ws8 + OFF_WT);
  ushort* qb  = (ushort*)(ws8 + OFF_Q);
  ushort* kkb = (ushort*)(ws8 + OFF_KK);
  ushort* Kt  = (ushort*)(ws8 + OFF_KT);
  ushort* Vt  = (ushort*)(ws8 + OFF_VT);
  ushort* Mt  = (ushort*)(ws8 + OFF_MT);
  ushort* Y   = (ushort*)(ws8 + OFF_Y);
  float*  zpH = (float*)(ws8 + OFF_ZP);

  constexpr int SMEM_QKVT = 65536, SMEM_H = 98304, SMEM_Y = 163840;
  hipFuncSetAttribute((const void*)k8_qkvt, hipFuncAttributeMaxDynamicSharedMemorySize, SMEM_QKVT);
  hipFuncSetAttribute((const void*)k8_y,    hipFuncAttributeMaxDynamicSharedMemorySize, SMEM_Y);
  hipFuncSetAttribute((const void*)k8_out,  hipFuncAttributeMaxDynamicSharedMemorySize, SMEM_H);

  k_pre<<<4352, 256, 0, stream>>>(x, Wq, Wk, Wv, Wp, xb, wt);
  k8_qkvt<<<512, 512, SMEM_QKVT, stream>>>(xb, wt, qb, kkb, Kt, Vt, zpH);
  k8_mtst<<<256, 512, 0, stream>>>(Kt, Vt, Mt);
  k8_y<<<256, 512, SMEM_Y, stream>>>(qb, kkb, Mt, Vt, zpH, Y);
  k8_out<<<256, 512, SMEM_H, stream>>>(Y, wt, out);
}

// Round 12
// 130.430 us; speedup vs baseline: 1.7770x; 1.0226x over previous
//
#include <hip/hip_runtime.h>

// Linear attention (B=8, T=2048, D=512), chunked, bf16 MFMA, fp32 acc.
// R12: z-fused qkvt, BK=32, TRIPLE-buffered (96KB LDS), prefetch depth 2 with
// counted vmcnt(4) per tile (T4: loads stay in flight across barriers).
//   k_pre   : bf16(x) + W^T transposes                          (4352 blocks)
//   k8_qkvt : q | kk+Kt^T+zsum | Vt^T fused per block           (512 blocks, 96KB LDS)
//   k8_mtst : St = exclusive-chunk-prefix(Vt_c Kt_c^T) fused    (256 blocks)
//   k8_y    : G=tril(QK^T)->LDS, den in-block, y=(QSt^T+GVt^T)/den (256 blocks, 160KB LDS)
//   k8_out  : out = y Wp^T (fp32)                               (256 blocks)
// All GEMMs are C = A * B^T with A:[M][K], B:[N][K] row-major bf16.

typedef __attribute__((ext_vector_type(4))) float f32x4;
typedef __attribute__((ext_vector_type(8))) __bf16 bf16x8;
typedef __attribute__((ext_vector_type(8))) unsigned short ushort8;

// ---- ws layout (byte offsets) ----
constexpr size_t OFF_XB  = 0;                  // bf16 [16384][512]
constexpr size_t OFF_WT  = OFF_XB + 16777216;  // bf16 4x [512][512] (WqT,WkT,WvT,WpT)
constexpr size_t OFF_Q   = OFF_WT + 2097152;   // bf16 [16384][512]
constexpr size_t OFF_KK  = OFF_Q  + 16777216;  // bf16 [16384][512]
constexpr size_t OFF_KT  = OFF_KK + 16777216;  // bf16 [512][16384]
constexpr size_t OFF_VT  = OFF_KT + 16777216;  // bf16 [512][16384]
constexpr size_t OFF_MT  = OFF_VT + 16777216;  // bf16 [64][512][512] St (prefixed)
constexpr size_t OFF_Y   = OFF_MT + 33554432;  // bf16 [16384][512]
constexpr size_t OFF_ZP  = OFF_Y  + 16777216;  // f32  [128][512] half-chunk col sums of kk
constexpr size_t WS_NEED = OFF_ZP + 262144;

__device__ __forceinline__ unsigned short bfbits(float f) {
  __bf16 h = (__bf16)f;
  return __builtin_bit_cast(unsigned short, h);
}
__device__ __forceinline__ float bff(unsigned short u) {
  return (float)__builtin_bit_cast(__bf16, u);
}

__device__ __forceinline__ void gload16(const void* g, void* l) {
  __builtin_amdgcn_global_load_lds((const __attribute__((address_space(1))) void*)g,
                                   (__attribute__((address_space(3))) void*)l, 16, 0, 0);
}

// ============ 128B-row stage/frag pair (mtst, y, out) — proven 0-conflict ============
__device__ __forceinline__ void stage_half(const char* gRow0, size_t ld2, int k0b,
                                           char* ldsHalf, int w, int lane) {
#pragma unroll
  for (int i = 0; i < 2; ++i) {
    int L = (w << 10) + (lane << 4) + (i << 13);
    int r = L >> 7;
    int cb = (L & 127) ^ ((r & 7) << 4);
    gload16(gRow0 + (size_t)r * ld2 + k0b + cb, ldsHalf + (w << 10) + (i << 13));
  }
}

__device__ __forceinline__ void stage_q64(const char* gRow0, size_t ld2, int k0b,
                                          char* lds, int tid) {
  int L = tid << 4;
  int r = L >> 7;
  int cb = (L & 127) ^ ((r & 7) << 4);
  gload16(gRow0 + (size_t)r * ld2 + k0b + cb, lds + L);
}

__device__ __forceinline__ const bf16x8* frag_at(const char* halfBase, int rowInHalf,
                                                 int colByte) {
  int lin = (rowInHalf << 7) + colByte;
  lin ^= (rowInHalf & 7) << 4;
  return (const bf16x8*)(halfBase + lin);
}

// ============ 64B-row stage/frag pair (qkvt BK=32 tiles: [128 rows][32 cols]) ============
// slot(r) = (4r + sw(r) ^ k) mod 8 with sw(r) = (r>>1)&3 covers each slot 2x -> free.
__device__ __forceinline__ void stage32s(const char* g, size_t ld2, int k0b,
                                         char* lds, int tid) {
  int L = tid << 4;  // 0..8191
  int r = L >> 6;    // row 0..127
  int cb = (L & 63) ^ (((r >> 1) & 3) << 4);
  gload16(g + (size_t)r * ld2 + k0b + cb, lds + L);
}

__device__ __forceinline__ const bf16x8* frag32s(const char* base, int row, int kB) {
  int lin = (row << 6) + (kB ^ (((row >> 1) & 3) << 4));
  return (const bf16x8*)(base + lin);
}

// ======================= 128x256 8-wave 4-phase core (y, out) =======================
#define QUADH(mh, nh)                                                                  \
  _Pragma("unroll") for (int mm = 0; mm < 2; ++mm)                                     \
  _Pragma("unroll") for (int nn = 0; nn < 2; ++nn)                                     \
  _Pragma("unroll") for (int s = 0; s < 2; ++s)                                        \
      acc[(mh)*2 + mm][(nh)*2 + nn] = __builtin_amdgcn_mfma_f32_16x16x32_bf16(         \
          af[(mh)*2 + mm][s], bg[(nh)*2 + nn][s], acc[(mh)*2 + mm][(nh)*2 + nn], 0, 0, 0);

#define PHASE_TAILH(MH, NH)                                      \
  __builtin_amdgcn_s_barrier();                                  \
  asm volatile("s_waitcnt lgkmcnt(0)" ::: "memory");             \
  __builtin_amdgcn_sched_barrier(0);                             \
  __builtin_amdgcn_s_setprio(1);                                 \
  QUADH(MH, NH);                                                 \
  __builtin_amdgcn_s_setprio(0);                                 \
  __builtin_amdgcn_s_barrier();

__device__ __forceinline__ void core8h(const char* Ab, size_t lda2, const char* Bb,
                                       size_t ldb2, int nt, char* sA, char* sB,
                                       f32x4 (&acc)[4][4], int w, int lane) {
  const int wr = w >> 2, wc = w & 3;
  const int fr = lane & 15, foB = (lane >> 4) << 4;
  const int brow = (wc & 1) << 6;
  const char* gB1 = Bb + (size_t)128 * ldb2;
  bf16x8 af[4][2], bg[4][2];

  stage_half(Ab, lda2, 0, sA + 0, w, lane);
  stage_half(Bb, ldb2, 0, sB + 0, w, lane);
  stage_half(gB1, ldb2, 0, sB + 16384, w, lane);
  if (nt > 1) {
    stage_half(Ab, lda2, 128, sA + 16384, w, lane);
    asm volatile("s_waitcnt vmcnt(2)" ::: "memory");
  } else {
    asm volatile("s_waitcnt vmcnt(0)" ::: "memory");
  }
  __builtin_amdgcn_sched_barrier(0);
  __builtin_amdgcn_s_barrier();

  for (int t = 0; t < nt; ++t) {
    const int buf = t & 1;
    const char* cA = sA + buf * 16384;
    const char* cB = sB + buf * 32768 + (wc >> 1) * 16384;
    char* nA = sA + buf * 16384;
    char* nB = sB + (buf ^ 1) * 32768;
    const int kb1 = (t + 1) << 7, kb2 = (t + 2) << 7;
    const bool stB = (t + 1 < nt), stA = (t + 2 < nt);

#pragma unroll
    for (int m = 0; m < 2; ++m)
#pragma unroll
      for (int s = 0; s < 2; ++s)
        af[m][s] = *frag_at(cA, wr * 64 + m * 16 + fr, s * 64 + foB);
#pragma unroll
    for (int n = 0; n < 2; ++n)
#pragma unroll
      for (int s = 0; s < 2; ++s)
        bg[n][s] = *frag_at(cB, brow + n * 16 + fr, s * 64 + foB);
    if (stB) stage_half(Bb, ldb2, kb1, nB + 0, w, lane);
    PHASE_TAILH(0, 0)

#pragma unroll
    for (int m = 2; m < 4; ++m)
#pragma unroll
      for (int s = 0; s < 2; ++s)
        af[m][s] = *frag_at(cA, wr * 64 + m * 16 + fr, s * 64 + foB);
    if (stB) stage_half(gB1, ldb2, kb1, nB + 16384, w, lane);
    PHASE_TAILH(1, 0)

#pragma unroll
    for (int n = 2; n < 4; ++n)
#pragma unroll
      for (int s = 0; s < 2; ++s)
        bg[n][s] = *frag_at(cB, brow + n * 16 + fr, s * 64 + foB);
    if (stA) stage_half(Ab, lda2, kb2, nA, w, lane);
    PHASE_TAILH(0, 1)

    if (t < nt - 1) {
      if (stA) {
        asm volatile("s_waitcnt vmcnt(2)" ::: "memory");
      } else {
        asm volatile("s_waitcnt vmcnt(0)" ::: "memory");
      }
      __builtin_amdgcn_sched_barrier(0);
    }
    PHASE_TAILH(1, 1)
  }
}

// ---- B-only-staging variant: A fixed in LDS (sG, 16 KB per K-tile) ----
__device__ __forceinline__ void core8h_ldsA(const char* sG, const char* Bb, size_t ldb2,
                                            int nt, char* sB, f32x4 (&acc)[4][4],
                                            int w, int lane) {
  const int wr = w >> 2, wc = w & 3;
  const int fr = lane & 15, foB = (lane >> 4) << 4;
  const int brow = (wc & 1) << 6;
  const char* gB1 = Bb + (size_t)128 * ldb2;
  bf16x8 af[4][2], bg[4][2];

  stage_half(Bb, ldb2, 0, sB + 0, w, lane);
  stage_half(gB1, ldb2, 0, sB + 16384, w, lane);
  asm volatile("s_waitcnt vmcnt(0)" ::: "memory");
  __builtin_amdgcn_sched_barrier(0);
  __builtin_amdgcn_s_barrier();

  for (int t = 0; t < nt; ++t) {
    const int buf = t & 1;
    const char* cA = sG + t * 16384;
    const char* cB = sB + buf * 32768 + (wc >> 1) * 16384;
    char* nB = sB + (buf ^ 1) * 32768;
    if (t + 1 < nt) {
      stage_half(Bb, ldb2, (t + 1) << 7, nB + 0, w, lane);
      stage_half(gB1, ldb2, (t + 1) << 7, nB + 16384, w, lane);
    }
#pragma unroll
    for (int m = 0; m < 4; ++m)
#pragma unroll
      for (int s = 0; s < 2; ++s)
        af[m][s] = *frag_at(cA, wr * 64 + m * 16 + fr, s * 64 + foB);
#pragma unroll
    for (int n = 0; n < 4; ++n)
#pragma unroll
      for (int s = 0; s < 2; ++s)
        bg[n][s] = *frag_at(cB, brow + n * 16 + fr, s * 64 + foB);
    __builtin_amdgcn_s_setprio(1);
#pragma unroll
    for (int m = 0; m < 4; ++m)
#pragma unroll
      for (int n = 0; n < 4; ++n)
#pragma unroll
        for (int s = 0; s < 2; ++s)
          acc[m][n] = __builtin_amdgcn_mfma_f32_16x16x32_bf16(af[m][s], bg[n][s],
                                                              acc[m][n], 0, 0, 0);
    __builtin_amdgcn_s_setprio(0);
    if (t + 1 < nt) {
      asm volatile("s_waitcnt vmcnt(0)" ::: "memory");
      __builtin_amdgcn_sched_barrier(0);
      __builtin_amdgcn_s_barrier();
    }
  }
}

#define ACC4_INIT                                    \
  f32x4 acc[4][4];                                   \
  _Pragma("unroll") for (int m_ = 0; m_ < 4; ++m_)   \
  _Pragma("unroll") for (int n_ = 0; n_ < 4; ++n_)   \
      acc[m_][n_] = f32x4{0.f, 0.f, 0.f, 0.f};

#define ACC4_ZERO                                    \
  _Pragma("unroll") for (int m_ = 0; m_ < 4; ++m_)   \
  _Pragma("unroll") for (int n_ = 0; n_ < 4; ++n_)   \
      acc[m_][n_] = f32x4{0.f, 0.f, 0.f, 0.f};

// ---- z-fused qkvt, BK=32, 3 buffers x 32KB, depth-2 prefetch, counted vmcnt ----
// Buffer layout: buf b at smem + b*32768: A @0, B0 @8K, B1 @16K, B2 @24K.
// Per tile: issue 4 gload16 (tile t+2), read 10 b128, 24 MFMA, vmcnt(4), barrier.
// vmcnt(4) = tile t+1's 4 loads stay in flight (never drain to 0 mid-loop).
__global__ __launch_bounds__(512, 2) void k8_qkvt(const ushort* __restrict__ xb,
                                                  const ushort* __restrict__ wt,
                                                  ushort* __restrict__ qb,
                                                  ushort* __restrict__ kkb,
                                                  ushort* __restrict__ Kt,
                                                  ushort* __restrict__ Vt,
                                                  float* __restrict__ zsumH) {
  extern __shared__ char smem[];
  const int o = blockIdx.x;
  const int wg = (o & 7) * 64 + (o >> 3);  // bijective: 512 % 8 == 0
  const int mt = wg >> 2, ct = wg & 3;
  const int tid = threadIdx.x, w = tid >> 6, lane = tid & 63;
  const int wr = w >> 2, wc = w & 3;
  const int fr = lane & 15, foB = (lane >> 4) << 4, q4 = (lane >> 4) << 2;
  const char* Ab = (const char*)(xb + (size_t)mt * 128 * 512);
  const char* Bz0 = (const char*)(wt + (size_t)ct * 65536);
  const char* Bz1 = (const char*)(wt + 262144 + (size_t)ct * 65536);
  const char* Bz2 = (const char*)(wt + 524288 + (size_t)ct * 65536);

  f32x4 acc[3][4][2];
#pragma unroll
  for (int z = 0; z < 3; ++z)
#pragma unroll
    for (int m = 0; m < 4; ++m)
#pragma unroll
      for (int n = 0; n < 2; ++n) acc[z][m][n] = f32x4{0.f, 0.f, 0.f, 0.f};

#define QSTAGE(t)                                              \
  {                                                            \
    char* bp_ = smem + ((t) % 3) * 32768;                      \
    const int kb_ = (t) << 6;                                  \
    stage32s(Ab, 1024, kb_, bp_, tid);                         \
    stage32s(Bz0, 1024, kb_, bp_ + 8192, tid);                 \
    stage32s(Bz1, 1024, kb_, bp_ + 16384, tid);                \
    stage32s(Bz2, 1024, kb_, bp_ + 24576, tid);                \
  }

  QSTAGE(0)
  QSTAGE(1)
  asm volatile("s_waitcnt vmcnt(4)" ::: "memory");  // tile 0 done; tile 1 in flight
  __builtin_amdgcn_sched_barrier(0);
  __builtin_amdgcn_s_barrier();

  for (int t = 0; t < 16; ++t) {
    const char* bp = smem + (t % 3) * 32768;
    if (t + 2 < 16) QSTAGE(t + 2)
    bf16x8 af[4], bg[3][2];
#pragma unroll
    for (int m = 0; m < 4; ++m)
      af[m] = *frag32s(bp, wr * 64 + m * 16 + fr, foB);
#pragma unroll
    for (int z = 0; z < 3; ++z)
#pragma unroll
      for (int n = 0; n < 2; ++n)
        bg[z][n] = *frag32s(bp + 8192 + z * 8192, wc * 32 + n * 16 + fr, foB);
    __builtin_amdgcn_s_setprio(1);
#pragma unroll
    for (int z = 0; z < 3; ++z)
#pragma unroll
      for (int m = 0; m < 4; ++m)
#pragma unroll
        for (int n = 0; n < 2; ++n)
          acc[z][m][n] = __builtin_amdgcn_mfma_f32_16x16x32_bf16(af[m], bg[z][n],
                                                                 acc[z][m][n], 0, 0, 0);
    __builtin_amdgcn_s_setprio(0);
    if (t + 1 < 16) {  // ensure tile t+1 resident before next iteration reads it
      if (t + 2 < 16) {
        asm volatile("s_waitcnt vmcnt(4)" ::: "memory");
      } else {
        asm volatile("s_waitcnt vmcnt(0)" ::: "memory");
      }
    }
    __builtin_amdgcn_sched_barrier(0);
    __builtin_amdgcn_s_barrier();
  }
#undef QSTAGE

  const size_t row0 = (size_t)mt * 128 + wr * 64;  // t index
  const size_t col0 = (size_t)ct * 128 + wc * 32;  // d index
  // z=0: q = phi(..)
#pragma unroll
  for (int m = 0; m < 4; ++m)
#pragma unroll
    for (int n = 0; n < 2; ++n)
#pragma unroll
      for (int r = 0; r < 4; ++r) {
        float v = acc[0][m][n][r];
        v = v > 0.f ? v + 1.f : __expf(v);
        qb[(row0 + m * 16 + q4 + r) * 512 + col0 + n * 16 + fr] = bfbits(v);
      }
  // z=2: Vt transposed
#pragma unroll
  for (int m = 0; m < 4; ++m)
#pragma unroll
    for (int n = 0; n < 2; ++n) {
      ushort4 ov;
      ov.x = bfbits(acc[2][m][n][0]);
      ov.y = bfbits(acc[2][m][n][1]);
      ov.z = bfbits(acc[2][m][n][2]);
      ov.w = bfbits(acc[2][m][n][3]);
      *(ushort4*)&Vt[(col0 + n * 16 + fr) * 16384 + row0 + m * 16 + q4] = ov;
    }
  // z=1: kk normal + Kt transposed + col sums
  float zs[2] = {0.f, 0.f};
#pragma unroll
  for (int m = 0; m < 4; ++m)
#pragma unroll
    for (int n = 0; n < 2; ++n) {
      float ph[4];
#pragma unroll
      for (int r = 0; r < 4; ++r) {
        float v = acc[1][m][n][r];
        ph[r] = v > 0.f ? v + 1.f : __expf(v);
        kkb[(row0 + m * 16 + q4 + r) * 512 + col0 + n * 16 + fr] = bfbits(ph[r]);
        zs[n] += ph[r];
      }
      ushort4 ov;
      ov.x = bfbits(ph[0]); ov.y = bfbits(ph[1]); ov.z = bfbits(ph[2]); ov.w = bfbits(ph[3]);
      *(ushort4*)&Kt[(col0 + n * 16 + fr) * 16384 + row0 + m * 16 + q4] = ov;
    }
#pragma unroll
  for (int n = 0; n < 2; ++n) {
    zs[n] += __shfl_xor(zs[n], 16, 64);
    zs[n] += __shfl_xor(zs[n], 32, 64);
  }
  float* zbuf = (float*)smem;  // safe: final K-loop barrier drained all reads
  if (lane < 16) {
#pragma unroll
    for (int n = 0; n < 2; ++n) zbuf[wr * 128 + wc * 32 + n * 16 + fr] = zs[n];
  }
  __syncthreads();
  if (tid < 128)
    zsumH[(size_t)mt * 512 + ct * 128 + tid] = zbuf[tid] + zbuf[128 + tid];
}

// ---- St = exclusive chunk prefix of Vt_c Kt_c^T, fused (per-tile chunk loop) ----
__global__ __launch_bounds__(512, 2) void k8_mtst(const ushort* __restrict__ Kt,
                                                  const ushort* __restrict__ Vt,
                                                  ushort* __restrict__ Mt) {
  __shared__ __align__(16) char smem[49152];  // A 2x16K @0, B 2x8K @32768
  const int o = blockIdx.x;
  const int wg = (o & 7) * 32 + (o >> 3);
  const int et = wg >> 6, b = (wg >> 3) & 7, dt = wg & 7;
  const int tid = threadIdx.x, w = tid >> 6, lane = tid & 63;
  const int wr = w >> 2, wc = w & 3, fr = lane & 15;
  const int foB = (lane >> 4) << 4, q4 = (lane >> 4) << 2;
  const char* Ab = (const char*)(Vt + (size_t)et * 128 * 16384 + b * 2048);
  const char* Bb = (const char*)(Kt + (size_t)dt * 64 * 16384 + b * 2048);
  f32x4 acc[4];
#pragma unroll
  for (int m = 0; m < 4; ++m) acc[m] = f32x4{0.f, 0.f, 0.f, 0.f};

  stage_half(Ab, 32768, 0, smem, w, lane);
  stage_q64(Bb, 32768, 0, smem + 32768, tid);
  asm volatile("s_waitcnt vmcnt(0)" ::: "memory");
  __builtin_amdgcn_sched_barrier(0);
  __builtin_amdgcn_s_barrier();

  const int colg = dt * 64 + wc * 16 + fr;
  for (int kk = 0; kk < 32; ++kk) {
    const int c = kk >> 2, buf = kk & 1;
    if ((kk & 3) == 0) {
      ushort* Sc = Mt + (size_t)(b * 8 + c) * 262144 + colg;
#pragma unroll
      for (int m = 0; m < 4; ++m)
#pragma unroll
        for (int r = 0; r < 4; ++r)
          Sc[(size_t)(et * 128 + wr * 64 + m * 16 + q4 + r) * 512] = bfbits(acc[m][r]);
    }
    if (kk + 1 < 32) {
      const int k0b = ((kk + 1) >> 2) * 512 + ((kk + 1) & 3) * 128;
      stage_half(Ab, 32768, k0b, smem + ((buf ^ 1) << 14), w, lane);
      stage_q64(Bb, 32768, k0b, smem + 32768 + ((buf ^ 1) << 13), tid);
    }
    const char* cA = smem + (buf << 14);
    const char* cB = smem + 32768 + (buf << 13);
    bf16x8 af[4][2], bg[2];
#pragma unroll
    for (int s = 0; s < 2; ++s) bg[s] = *frag_at(cB, wc * 16 + fr, s * 64 + foB);
#pragma unroll
    for (int m = 0; m < 4; ++m)
#pragma unroll
      for (int s = 0; s < 2; ++s)
        af[m][s] = *frag_at(cA, wr * 64 + m * 16 + fr, s * 64 + foB);
    __builtin_amdgcn_s_setprio(1);
#pragma unroll
    for (int m = 0; m < 4; ++m)
#pragma unroll
      for (int s = 0; s < 2; ++s)
        acc[m] = __builtin_amdgcn_mfma_f32_16x16x32_bf16(af[m][s], bg[s], acc[m], 0, 0, 0);
    __builtin_amdgcn_s_setprio(0);
    asm volatile("s_waitcnt vmcnt(0)" ::: "memory");
    __builtin_amdgcn_sched_barrier(0);
    __builtin_amdgcn_s_barrier();
  }
}

// ---- y uber-kernel: G(LDS) + den in-block + y = (Q St^T + G Vt^T)/den ----
__global__ __launch_bounds__(512, 2) void k8_y(const ushort* __restrict__ qb,
                                               const ushort* __restrict__ kkb,
                                               const ushort* __restrict__ St,
                                               const ushort* __restrict__ Vt,
                                               const float* __restrict__ zsumH,
                                               ushort* __restrict__ Y) {
  extern __shared__ char smem[];
  const int o = blockIdx.x;
  const int wg = (o & 7) * 32 + (o >> 3);
  const int bc = wg >> 2, rh = (wg >> 1) & 1, ch = wg & 1;
  const int b = bc >> 3, c = bc & 7;
  const int tid = threadIdx.x, w = tid >> 6, lane = tid & 63;
  const int wr = w >> 2, wc = w & 3, fr = lane & 15, q4 = (lane >> 4) << 2;
  char* sA = smem + 65536;
  char* sB = smem + 98304;
  const char* qptr = (const char*)(qb + (size_t)bc * 131072 + (size_t)rh * 65536);

  ACC4_INIT
  core8h(qptr, 1024, (const char*)(kkb + (size_t)bc * 131072), 1024, 8, sA, sB, acc, w, lane);

  float rs[4][4];
#pragma unroll
  for (int m = 0; m < 4; ++m)
#pragma unroll
    for (int r = 0; r < 4; ++r) rs[m][r] = 0.f;
#pragma unroll
  for (int m = 0; m < 4; ++m)
#pragma unroll
    for (int n = 0; n < 4; ++n)
#pragma unroll
      for (int r = 0; r < 4; ++r) {
        int rowL = wr * 64 + m * 16 + q4 + r;
        int col = wc * 64 + n * 16 + fr;
        float v = (col <= rh * 128 + rowL) ? acc[m][n][r] : 0.f;
        rs[m][r] += v;
        int byte = (rowL << 7) + ((col & 63) << 1);
        byte ^= (rowL & 7) << 4;
        *(__bf16*)(smem + (wc << 14) + byte) = (__bf16)v;
      }
#pragma unroll
  for (int m = 0; m < 4; ++m)
#pragma unroll
    for (int r = 0; r < 4; ++r) {
      rs[m][r] += __shfl_xor(rs[m][r], 1, 64);
      rs[m][r] += __shfl_xor(rs[m][r], 2, 64);
      rs[m][r] += __shfl_xor(rs[m][r], 4, 64);
      rs[m][r] += __shfl_xor(rs[m][r], 8, 64);
    }
  float* red = (float*)sA;
  float* zpl = red + 512;
  float* dend = zpl + 512;
  if (fr == 0) {
#pragma unroll
    for (int m = 0; m < 4; ++m)
#pragma unroll
      for (int r = 0; r < 4; ++r) red[wc * 128 + wr * 64 + m * 16 + q4 + r] = rs[m][r];
  }
  {
    float a = 0.f;
    for (int cp = 0; cp < c; ++cp)
      a += zsumH[(size_t)((b * 8 + cp) * 2) * 512 + tid] +
           zsumH[(size_t)((b * 8 + cp) * 2 + 1) * 512 + tid];
    zpl[tid] = a;
  }
  __syncthreads();
  {
    int rl = tid >> 2, quarter = tid & 3;
    int trow = bc * 256 + rh * 128 + rl;
    const ushort* qrow = qb + (size_t)trow * 512 + quarter * 128;
    const float* zq = zpl + quarter * 128;
    float s = 0.f;
    for (int j = 0; j < 128; j += 8) {
      ushort8 qv = *(const ushort8*)&qrow[j];
#pragma unroll
      for (int u = 0; u < 8; ++u) s = fmaf(bff(qv[u]), zq[j + u], s);
    }
    s += __shfl_xor(s, 1, 64);
    s += __shfl_xor(s, 2, 64);
    if (quarter == 0)
      dend[rl] = s + red[rl] + red[128 + rl] + red[256 + rl] + red[384 + rl] + 1e-6f;
  }
  __syncthreads();
  float dinv[4][4];
#pragma unroll
  for (int m = 0; m < 4; ++m)
#pragma unroll
    for (int r = 0; r < 4; ++r) dinv[m][r] = 1.f / dend[wr * 64 + m * 16 + q4 + r];
  __syncthreads();

  ACC4_ZERO
  core8h(qptr, 1024, (const char*)(St + (size_t)bc * 262144 + (size_t)ch * 131072), 1024, 8,
         sA, sB, acc, w, lane);
  core8h_ldsA(smem, (const char*)(Vt + (size_t)ch * 256 * 16384 + (size_t)bc * 256), 32768,
              rh ? 4 : 2, sB, acc, w, lane);

#pragma unroll
  for (int m = 0; m < 4; ++m)
#pragma unroll
    for (int n = 0; n < 4; ++n)
#pragma unroll
      for (int r = 0; r < 4; ++r) {
        size_t row = (size_t)bc * 256 + rh * 128 + wr * 64 + m * 16 + q4 + r;
        size_t col = (size_t)ch * 256 + wc * 64 + n * 16 + fr;
        Y[row * 512 + col] = bfbits(acc[m][n][r] * dinv[m][r]);
      }
}

// ---- out = Y WpT^T (fp32) : 256 blocks, core8h ----
__global__ __launch_bounds__(512, 2) void k8_out(const ushort* __restrict__ Y,
                                                 const ushort* __restrict__ wt,
                                                 float* __restrict__ out) {
  extern __shared__ char smem[];
  const int o = blockIdx.x;
  const int wg = (o & 7) * 32 + (o >> 3);
  const int mt = wg >> 1, ct = wg & 1;
  const int tid = threadIdx.x, w = tid >> 6, lane = tid & 63;
  ACC4_INIT
  core8h((const char*)(Y + (size_t)mt * 65536), 1024,
         (const char*)(wt + 786432 + (size_t)ct * 131072), 1024, 8,
         smem, smem + 32768, acc, w, lane);
  const int wr = w >> 2, wc = w & 3, fr = lane & 15, q4 = (lane >> 4) << 2;
  const size_t row0 = (size_t)mt * 128 + wr * 64;
  const size_t col0 = (size_t)ct * 256 + wc * 64;
#pragma unroll
  for (int m = 0; m < 4; ++m)
#pragma unroll
    for (int n = 0; n < 4; ++n)
#pragma unroll
      for (int r = 0; r < 4; ++r)
        out[(row0 + m * 16 + q4 + r) * 512 + col0 + n * 16 + fr] = acc[m][n][r];
}

// ---- x -> bf16 (4096 blocks) + W -> W^T bf16 (256 blocks) ----
__global__ __launch_bounds__(256) void k_pre(const float* __restrict__ x,
                                             const float* __restrict__ Wq,
                                             const float* __restrict__ Wk,
                                             const float* __restrict__ Wv,
                                             const float* __restrict__ Wp,
                                             ushort* __restrict__ xb,
                                             ushort* __restrict__ wt) {
  __shared__ float tile[64][65];
  if (blockIdx.x < 4096) {
    size_t i = ((size_t)blockIdx.x * 256 + threadIdx.x) * 8;
    float4 f0 = *(const float4*)&x[i], f1 = *(const float4*)&x[i + 4];
    ushort8 ov;
    ov[0] = bfbits(f0.x); ov[1] = bfbits(f0.y); ov[2] = bfbits(f0.z); ov[3] = bfbits(f0.w);
    ov[4] = bfbits(f1.x); ov[5] = bfbits(f1.y); ov[6] = bfbits(f1.z); ov[7] = bfbits(f1.w);
    *(ushort8*)&xb[i] = ov;
  } else {
    const int g = blockIdx.x - 4096;
    const int bz = g >> 6, rem = g & 63, bxw = rem >> 3, byw = rem & 7;
    const float* src = bz == 0 ? Wq : bz == 1 ? Wk : bz == 2 ? Wv : Wp;
    ushort* dst = wt + (size_t)bz * 262144;
    const int d0 = bxw * 64, n0 = byw * 64;
    const int tr = threadIdx.x >> 4, tc = (threadIdx.x & 15) << 2;
#pragma unroll
    for (int it = 0; it < 4; ++it) {
      float4 f = *(const float4*)&src[(size_t)(d0 + it * 16 + tr) * 512 + n0 + tc];
      tile[it * 16 + tr][tc + 0] = f.x;
      tile[it * 16 + tr][tc + 1] = f.y;
      tile[it * 16 + tr][tc + 2] = f.z;
      tile[it * 16 + tr][tc + 3] = f.w;
    }
    __syncthreads();
#pragma unroll
    for (int it = 0; it < 4; ++it) {
      int n = it * 16 + tr;
      ushort4 ov;
      ov.x = bfbits(tile[tc + 0][n]);
      ov.y = bfbits(tile[tc + 1][n]);
      ov.z = bfbits(tile[tc + 2][n]);
      ov.w = bfbits(tile[tc + 3][n]);
      *(ushort4*)&dst[(size_t)(n0 + n) * 512 + d0 + tc] = ov;
    }
  }
}

extern "C" void kernel_launch(void* const* d_in, const int* in_sizes, int n_in,
                              void* d_out, int out_size, void* d_ws, size_t ws_size,
                              hipStream_t stream) {
  const float* x  = (const float*)d_in[0];
  const float* Wq = (const float*)d_in[1];
  const float* Wk = (const float*)d_in[2];
  const float* Wv = (const float*)d_in[3];
  const float* Wp = (const float*)d_in[4];
  float* out = (float*)d_out;
  char* ws8 = (char*)d_ws;
  if (ws_size < WS_NEED) return;

  ushort* xb  = (ushort*)(ws8 + OFF_XB);
  ushort* wt  = (ushort*)(ws8 + OFF_WT);
  ushort* qb  = (ushort*)(ws8 + OFF_Q);
  ushort* kkb = (ushort*)(ws8 + OFF_KK);
  ushort* Kt  = (ushort*)(ws8 + OFF_KT);
  ushort* Vt  = (ushort*)(ws8 + OFF_VT);
  ushort* Mt  = (ushort*)(ws8 + OFF_MT);
  ushort* Y   = (ushort*)(ws8 + OFF_Y);
  float*  zpH = (float*)(ws8 + OFF_ZP);

  constexpr int SMEM_QKVT = 98304, SMEM_H = 98304, SMEM_Y = 163840;
  hipFuncSetAttribute((const void*)k8_qkvt, hipFuncAttributeMaxDynamicSharedMemorySize, SMEM_QKVT);
  hipFuncSetAttribute((const void*)k8_y,    hipFuncAttributeMaxDynamicSharedMemorySize, SMEM_Y);
  hipFuncSetAttribute((const void*)k8_out,  hipFuncAttributeMaxDynamicSharedMemorySize, SMEM_H);

  k_pre<<<4352, 256, 0, stream>>>(x, Wq, Wk, Wv, Wp, xb, wt);
  k8_qkvt<<<512, 512, SMEM_QKVT, stream>>>(xb, wt, qb, kkb, Kt, Vt, zpH);
  k8_mtst<<<256, 512, 0, stream>>>(Kt, Vt, Mt);
  k8_y<<<256, 512, SMEM_Y, stream>>>(qb, kkb, Mt, Vt, zpH, Y);
  k8_out<<<256, 512, SMEM_H, stream>>>(Y, wt, out);
}

// Round 13
// 130.019 us; speedup vs baseline: 1.7826x; 1.0032x over previous
//
#include <hip/hip_runtime.h>

// Linear attention (B=8, T=2048, D=512), chunked, bf16 MFMA, fp32 acc.
// R13: R9 base; x->bf16 conversion fused INTO qkvt's A-staging (T14 split:
// fp32 loads at loop top, cvt+ds_write after MFMA burst). k_pre = W^T only.
//   k_pre   : W^T transposes only                               (256 blocks)
//   k8_qkvt : q | kk+Kt^T+zsum | Vt^T fused, A from fp32 x      (512 blocks, 128KB LDS)
//   k8_mtst : St = exclusive-chunk-prefix(Vt_c Kt_c^T) fused    (256 blocks)
//   k8_y    : G=tril(QK^T)->LDS, den in-block, y=(QSt^T+GVt^T)/den (256 blocks, 160KB LDS)
//   k8_out  : out = y Wp^T (fp32)                               (256 blocks)
// All GEMMs are C = A * B^T with A:[M][K], B:[N][K] row-major bf16.

typedef __attribute__((ext_vector_type(4))) float f32x4;
typedef __attribute__((ext_vector_type(8))) __bf16 bf16x8;
typedef __attribute__((ext_vector_type(8))) unsigned short ushort8;

// ---- ws layout (byte offsets; XB slot retained but unused) ----
constexpr size_t OFF_XB  = 0;
constexpr size_t OFF_WT  = OFF_XB + 16777216;  // bf16 4x [512][512] (WqT,WkT,WvT,WpT)
constexpr size_t OFF_Q   = OFF_WT + 2097152;   // bf16 [16384][512]
constexpr size_t OFF_KK  = OFF_Q  + 16777216;  // bf16 [16384][512]
constexpr size_t OFF_KT  = OFF_KK + 16777216;  // bf16 [512][16384]
constexpr size_t OFF_VT  = OFF_KT + 16777216;  // bf16 [512][16384]
constexpr size_t OFF_MT  = OFF_VT + 16777216;  // bf16 [64][512][512] St (prefixed)
constexpr size_t OFF_Y   = OFF_MT + 33554432;  // bf16 [16384][512]
constexpr size_t OFF_ZP  = OFF_Y  + 16777216;  // f32  [128][512] col sums of kk
constexpr size_t WS_NEED = OFF_ZP + 262144;

__device__ __forceinline__ unsigned short bfbits(float f) {
  __bf16 h = (__bf16)f;
  return __builtin_bit_cast(unsigned short, h);
}
__device__ __forceinline__ float bff(unsigned short u) {
  return (float)__builtin_bit_cast(__bf16, u);
}

__device__ __forceinline__ void gload16(const void* g, void* l) {
  __builtin_amdgcn_global_load_lds((const __attribute__((address_space(1))) void*)g,
                                   (__attribute__((address_space(3))) void*)l, 16, 0, 0);
}

// ============ 128B-row stage/frag pair — proven 0-conflict ============
__device__ __forceinline__ void stage_half(const char* gRow0, size_t ld2, int k0b,
                                           char* ldsHalf, int w, int lane) {
#pragma unroll
  for (int i = 0; i < 2; ++i) {
    int L = (w << 10) + (lane << 4) + (i << 13);
    int r = L >> 7;
    int cb = (L & 127) ^ ((r & 7) << 4);
    gload16(gRow0 + (size_t)r * ld2 + k0b + cb, ldsHalf + (w << 10) + (i << 13));
  }
}

__device__ __forceinline__ void stage_q64(const char* gRow0, size_t ld2, int k0b,
                                          char* lds, int tid) {
  int L = tid << 4;
  int r = L >> 7;
  int cb = (L & 127) ^ ((r & 7) << 4);
  gload16(gRow0 + (size_t)r * ld2 + k0b + cb, lds + L);
}

__device__ __forceinline__ const bf16x8* frag_at(const char* halfBase, int rowInHalf,
                                                 int colByte) {
  int lin = (rowInHalf << 7) + colByte;
  lin ^= (rowInHalf & 7) << 4;
  return (const bf16x8*)(halfBase + lin);
}

// ---- fp32-A staging pair: same LDS mapping as stage_half, but the global
// source is fp32 x (row stride 2048B); load early, cvt+write late (T14). ----
__device__ __forceinline__ void ldA_f32(const char* Ax, int kb, int w, int lane,
                                        float4 (&v)[2][2]) {
#pragma unroll
  for (int i = 0; i < 2; ++i) {
    int L = (w << 10) + (lane << 4) + (i << 13);
    int r = L >> 7;
    int cb = (L & 127) ^ ((r & 7) << 4);
    const char* g = Ax + (size_t)r * 2048 + ((size_t)kb << 1) + (cb << 1);
    v[i][0] = *(const float4*)(g);
    v[i][1] = *(const float4*)(g + 16);
  }
}

__device__ __forceinline__ void wrA_bf16(char* ldsHalf, int w, int lane,
                                         const float4 (&v)[2][2]) {
#pragma unroll
  for (int i = 0; i < 2; ++i) {
    int L = (w << 10) + (lane << 4) + (i << 13);
    ushort8 o;
    o[0] = bfbits(v[i][0].x); o[1] = bfbits(v[i][0].y);
    o[2] = bfbits(v[i][0].z); o[3] = bfbits(v[i][0].w);
    o[4] = bfbits(v[i][1].x); o[5] = bfbits(v[i][1].y);
    o[6] = bfbits(v[i][1].z); o[7] = bfbits(v[i][1].w);
    *(ushort8*)(ldsHalf + L) = o;
  }
}

// ======================= 128x256 8-wave 4-phase core (y, out) =======================
#define QUADH(mh, nh)                                                                  \
  _Pragma("unroll") for (int mm = 0; mm < 2; ++mm)                                     \
  _Pragma("unroll") for (int nn = 0; nn < 2; ++nn)                                     \
  _Pragma("unroll") for (int s = 0; s < 2; ++s)                                        \
      acc[(mh)*2 + mm][(nh)*2 + nn] = __builtin_amdgcn_mfma_f32_16x16x32_bf16(         \
          af[(mh)*2 + mm][s], bg[(nh)*2 + nn][s], acc[(mh)*2 + mm][(nh)*2 + nn], 0, 0, 0);

#define PHASE_TAILH(MH, NH)                                      \
  __builtin_amdgcn_s_barrier();                                  \
  asm volatile("s_waitcnt lgkmcnt(0)" ::: "memory");             \
  __builtin_amdgcn_sched_barrier(0);                             \
  __builtin_amdgcn_s_setprio(1);                                 \
  QUADH(MH, NH);                                                 \
  __builtin_amdgcn_s_setprio(0);                                 \
  __builtin_amdgcn_s_barrier();

__device__ __forceinline__ void core8h(const char* Ab, size_t lda2, const char* Bb,
                                       size_t ldb2, int nt, char* sA, char* sB,
                                       f32x4 (&acc)[4][4], int w, int lane) {
  const int wr = w >> 2, wc = w & 3;
  const int fr = lane & 15, foB = (lane >> 4) << 4;
  const int brow = (wc & 1) << 6;
  const char* gB1 = Bb + (size_t)128 * ldb2;
  bf16x8 af[4][2], bg[4][2];

  stage_half(Ab, lda2, 0, sA + 0, w, lane);
  stage_half(Bb, ldb2, 0, sB + 0, w, lane);
  stage_half(gB1, ldb2, 0, sB + 16384, w, lane);
  if (nt > 1) {
    stage_half(Ab, lda2, 128, sA + 16384, w, lane);
    asm volatile("s_waitcnt vmcnt(2)" ::: "memory");
  } else {
    asm volatile("s_waitcnt vmcnt(0)" ::: "memory");
  }
  __builtin_amdgcn_sched_barrier(0);
  __builtin_amdgcn_s_barrier();

  for (int t = 0; t < nt; ++t) {
    const int buf = t & 1;
    const char* cA = sA + buf * 16384;
    const char* cB = sB + buf * 32768 + (wc >> 1) * 16384;
    char* nA = sA + buf * 16384;
    char* nB = sB + (buf ^ 1) * 32768;
    const int kb1 = (t + 1) << 7, kb2 = (t + 2) << 7;
    const bool stB = (t + 1 < nt), stA = (t + 2 < nt);

#pragma unroll
    for (int m = 0; m < 2; ++m)
#pragma unroll
      for (int s = 0; s < 2; ++s)
        af[m][s] = *frag_at(cA, wr * 64 + m * 16 + fr, s * 64 + foB);
#pragma unroll
    for (int n = 0; n < 2; ++n)
#pragma unroll
      for (int s = 0; s < 2; ++s)
        bg[n][s] = *frag_at(cB, brow + n * 16 + fr, s * 64 + foB);
    if (stB) stage_half(Bb, ldb2, kb1, nB + 0, w, lane);
    PHASE_TAILH(0, 0)

#pragma unroll
    for (int m = 2; m < 4; ++m)
#pragma unroll
      for (int s = 0; s < 2; ++s)
        af[m][s] = *frag_at(cA, wr * 64 + m * 16 + fr, s * 64 + foB);
    if (stB) stage_half(gB1, ldb2, kb1, nB + 16384, w, lane);
    PHASE_TAILH(1, 0)

#pragma unroll
    for (int n = 2; n < 4; ++n)
#pragma unroll
      for (int s = 0; s < 2; ++s)
        bg[n][s] = *frag_at(cB, brow + n * 16 + fr, s * 64 + foB);
    if (stA) stage_half(Ab, lda2, kb2, nA, w, lane);
    PHASE_TAILH(0, 1)

    if (t < nt - 1) {
      if (stA) {
        asm volatile("s_waitcnt vmcnt(2)" ::: "memory");
      } else {
        asm volatile("s_waitcnt vmcnt(0)" ::: "memory");
      }
      __builtin_amdgcn_sched_barrier(0);
    }
    PHASE_TAILH(1, 1)
  }
}

// ---- B-only-staging variant: A fixed in LDS (sG, 16 KB per K-tile) ----
__device__ __forceinline__ void core8h_ldsA(const char* sG, const char* Bb, size_t ldb2,
                                            int nt, char* sB, f32x4 (&acc)[4][4],
                                            int w, int lane) {
  const int wr = w >> 2, wc = w & 3;
  const int fr = lane & 15, foB = (lane >> 4) << 4;
  const int brow = (wc & 1) << 6;
  const char* gB1 = Bb + (size_t)128 * ldb2;
  bf16x8 af[4][2], bg[4][2];

  stage_half(Bb, ldb2, 0, sB + 0, w, lane);
  stage_half(gB1, ldb2, 0, sB + 16384, w, lane);
  asm volatile("s_waitcnt vmcnt(0)" ::: "memory");
  __builtin_amdgcn_sched_barrier(0);
  __builtin_amdgcn_s_barrier();

  for (int t = 0; t < nt; ++t) {
    const int buf = t & 1;
    const char* cA = sG + t * 16384;
    const char* cB = sB + buf * 32768 + (wc >> 1) * 16384;
    char* nB = sB + (buf ^ 1) * 32768;
    if (t + 1 < nt) {
      stage_half(Bb, ldb2, (t + 1) << 7, nB + 0, w, lane);
      stage_half(gB1, ldb2, (t + 1) << 7, nB + 16384, w, lane);
    }
#pragma unroll
    for (int m = 0; m < 4; ++m)
#pragma unroll
      for (int s = 0; s < 2; ++s)
        af[m][s] = *frag_at(cA, wr * 64 + m * 16 + fr, s * 64 + foB);
#pragma unroll
    for (int n = 0; n < 4; ++n)
#pragma unroll
      for (int s = 0; s < 2; ++s)
        bg[n][s] = *frag_at(cB, brow + n * 16 + fr, s * 64 + foB);
    __builtin_amdgcn_s_setprio(1);
#pragma unroll
    for (int m = 0; m < 4; ++m)
#pragma unroll
      for (int n = 0; n < 4; ++n)
#pragma unroll
        for (int s = 0; s < 2; ++s)
          acc[m][n] = __builtin_amdgcn_mfma_f32_16x16x32_bf16(af[m][s], bg[n][s],
                                                              acc[m][n], 0, 0, 0);
    __builtin_amdgcn_s_setprio(0);
    if (t + 1 < nt) {
      asm volatile("s_waitcnt vmcnt(0)" ::: "memory");
      __builtin_amdgcn_sched_barrier(0);
      __builtin_amdgcn_s_barrier();
    }
  }
}

#define ACC4_INIT                                    \
  f32x4 acc[4][4];                                   \
  _Pragma("unroll") for (int m_ = 0; m_ < 4; ++m_)   \
  _Pragma("unroll") for (int n_ = 0; n_ < 4; ++n_)   \
      acc[m_][n_] = f32x4{0.f, 0.f, 0.f, 0.f};

#define ACC4_ZERO                                    \
  _Pragma("unroll") for (int m_ = 0; m_ < 4; ++m_)   \
  _Pragma("unroll") for (int n_ = 0; n_ < 4; ++n_)   \
      acc[m_][n_] = f32x4{0.f, 0.f, 0.f, 0.f};

// ---- z-fused qkvt: A staged from fp32 x via ldA/wrA split; B via gload_lds ----
// LDS 128KB: sA dbuf 2x16K @0; B_z dbuf 2x16K @ 32K + z*32K.
__global__ __launch_bounds__(512, 2) void k8_qkvt(const float* __restrict__ xf,
                                                  const ushort* __restrict__ wt,
                                                  ushort* __restrict__ qb,
                                                  ushort* __restrict__ kkb,
                                                  ushort* __restrict__ Kt,
                                                  ushort* __restrict__ Vt,
                                                  float* __restrict__ zsumH) {
  extern __shared__ char smem[];
  const int o = blockIdx.x;
  const int wg = (o & 7) * 64 + (o >> 3);  // bijective: 512 % 8 == 0
  const int mt = wg >> 2, ct = wg & 3;
  const int tid = threadIdx.x, w = tid >> 6, lane = tid & 63;
  const int wr = w >> 2, wc = w & 3;
  const int fr = lane & 15, foB = (lane >> 4) << 4, q4 = (lane >> 4) << 2;
  const char* Ax = (const char*)xf + (size_t)mt * 128 * 2048;  // fp32 rows
  const char* Bz0 = (const char*)(wt + (size_t)ct * 65536);
  const char* Bz1 = (const char*)(wt + 262144 + (size_t)ct * 65536);
  const char* Bz2 = (const char*)(wt + 524288 + (size_t)ct * 65536);
  char* sA = smem;
  char* sB0 = smem + 32768;
  char* sB1 = smem + 65536;
  char* sB2 = smem + 98304;

  f32x4 acc[3][4][2];
#pragma unroll
  for (int z = 0; z < 3; ++z)
#pragma unroll
    for (int m = 0; m < 4; ++m)
#pragma unroll
      for (int n = 0; n < 2; ++n) acc[z][m][n] = f32x4{0.f, 0.f, 0.f, 0.f};

  float4 av[2][2];
  ldA_f32(Ax, 0, w, lane, av);
  stage_half(Bz0, 1024, 0, sB0, w, lane);
  stage_half(Bz1, 1024, 0, sB1, w, lane);
  stage_half(Bz2, 1024, 0, sB2, w, lane);
  wrA_bf16(sA, w, lane, av);
  asm volatile("s_waitcnt vmcnt(0) lgkmcnt(0)" ::: "memory");
  __builtin_amdgcn_sched_barrier(0);
  __builtin_amdgcn_s_barrier();

  for (int t = 0; t < 8; ++t) {
    const int buf = t & 1;
    const int bo = buf << 14, nbo = (buf ^ 1) << 14;
    if (t + 1 < 8) {  // issue next tile's loads first; they land under the MFMAs
      const int kb = (t + 1) << 7;
      ldA_f32(Ax, kb, w, lane, av);
      stage_half(Bz0, 1024, kb, sB0 + nbo, w, lane);
      stage_half(Bz1, 1024, kb, sB1 + nbo, w, lane);
      stage_half(Bz2, 1024, kb, sB2 + nbo, w, lane);
    }
    bf16x8 af[4][2], bg[3][2][2];
#pragma unroll
    for (int m = 0; m < 4; ++m)
#pragma unroll
      for (int s = 0; s < 2; ++s)
        af[m][s] = *frag_at(sA + bo, wr * 64 + m * 16 + fr, s * 64 + foB);
#pragma unroll
    for (int z = 0; z < 3; ++z)
#pragma unroll
      for (int n = 0; n < 2; ++n)
#pragma unroll
        for (int s = 0; s < 2; ++s)
          bg[z][n][s] = *frag_at((z == 0 ? sB0 : z == 1 ? sB1 : sB2) + bo,
                                 wc * 32 + n * 16 + fr, s * 64 + foB);
    __builtin_amdgcn_s_setprio(1);
#pragma unroll
    for (int z = 0; z < 3; ++z)
#pragma unroll
      for (int m = 0; m < 4; ++m)
#pragma unroll
        for (int n = 0; n < 2; ++n)
#pragma unroll
          for (int s = 0; s < 2; ++s)
            acc[z][m][n] = __builtin_amdgcn_mfma_f32_16x16x32_bf16(af[m][s], bg[z][n][s],
                                                                   acc[z][m][n], 0, 0, 0);
    __builtin_amdgcn_s_setprio(0);
    __builtin_amdgcn_sched_barrier(0);  // keep cvt+ds_write AFTER the MFMA burst
    if (t + 1 < 8) wrA_bf16(sA + nbo, w, lane, av);
    asm volatile("s_waitcnt vmcnt(0) lgkmcnt(0)" ::: "memory");
    __builtin_amdgcn_sched_barrier(0);
    __builtin_amdgcn_s_barrier();
  }

  const size_t row0 = (size_t)mt * 128 + wr * 64;  // t index
  const size_t col0 = (size_t)ct * 128 + wc * 32;  // d index
  // z=0: q = phi(..)
#pragma unroll
  for (int m = 0; m < 4; ++m)
#pragma unroll
    for (int n = 0; n < 2; ++n)
#pragma unroll
      for (int r = 0; r < 4; ++r) {
        float v = acc[0][m][n][r];
        v = v > 0.f ? v + 1.f : __expf(v);
        qb[(row0 + m * 16 + q4 + r) * 512 + col0 + n * 16 + fr] = bfbits(v);
      }
  // z=2: Vt transposed
#pragma unroll
  for (int m = 0; m < 4; ++m)
#pragma unroll
    for (int n = 0; n < 2; ++n) {
      ushort4 ov;
      ov.x = bfbits(acc[2][m][n][0]);
      ov.y = bfbits(acc[2][m][n][1]);
      ov.z = bfbits(acc[2][m][n][2]);
      ov.w = bfbits(acc[2][m][n][3]);
      *(ushort4*)&Vt[(col0 + n * 16 + fr) * 16384 + row0 + m * 16 + q4] = ov;
    }
  // z=1: kk normal + Kt transposed + col sums
  float zs[2] = {0.f, 0.f};
#pragma unroll
  for (int m = 0; m < 4; ++m)
#pragma unroll
    for (int n = 0; n < 2; ++n) {
      float ph[4];
#pragma unroll
      for (int r = 0; r < 4; ++r) {
        float v = acc[1][m][n][r];
        ph[r] = v > 0.f ? v + 1.f : __expf(v);
        kkb[(row0 + m * 16 + q4 + r) * 512 + col0 + n * 16 + fr] = bfbits(ph[r]);
        zs[n] += ph[r];
      }
      ushort4 ov;
      ov.x = bfbits(ph[0]); ov.y = bfbits(ph[1]); ov.z = bfbits(ph[2]); ov.w = bfbits(ph[3]);
      *(ushort4*)&Kt[(col0 + n * 16 + fr) * 16384 + row0 + m * 16 + q4] = ov;
    }
#pragma unroll
  for (int n = 0; n < 2; ++n) {
    zs[n] += __shfl_xor(zs[n], 16, 64);
    zs[n] += __shfl_xor(zs[n], 32, 64);
  }
  float* zbuf = (float*)smem;  // final K-loop barrier protects reuse
  if (lane < 16) {
#pragma unroll
    for (int n = 0; n < 2; ++n) zbuf[wr * 128 + wc * 32 + n * 16 + fr] = zs[n];
  }
  __syncthreads();
  if (tid < 128)
    zsumH[(size_t)mt * 512 + ct * 128 + tid] = zbuf[tid] + zbuf[128 + tid];
}

// ---- St = exclusive chunk prefix of Vt_c Kt_c^T, fused (per-tile chunk loop) ----
__global__ __launch_bounds__(512, 2) void k8_mtst(const ushort* __restrict__ Kt,
                                                  const ushort* __restrict__ Vt,
                                                  ushort* __restrict__ Mt) {
  __shared__ __align__(16) char smem[49152];  // A 2x16K @0, B 2x8K @32768
  const int o = blockIdx.x;
  const int wg = (o & 7) * 32 + (o >> 3);
  const int et = wg >> 6, b = (wg >> 3) & 7, dt = wg & 7;
  const int tid = threadIdx.x, w = tid >> 6, lane = tid & 63;
  const int wr = w >> 2, wc = w & 3, fr = lane & 15;
  const int foB = (lane >> 4) << 4, q4 = (lane >> 4) << 2;
  const char* Ab = (const char*)(Vt + (size_t)et * 128 * 16384 + b * 2048);
  const char* Bb = (const char*)(Kt + (size_t)dt * 64 * 16384 + b * 2048);
  f32x4 acc[4];
#pragma unroll
  for (int m = 0; m < 4; ++m) acc[m] = f32x4{0.f, 0.f, 0.f, 0.f};

  stage_half(Ab, 32768, 0, smem, w, lane);
  stage_q64(Bb, 32768, 0, smem + 32768, tid);
  asm volatile("s_waitcnt vmcnt(0)" ::: "memory");
  __builtin_amdgcn_sched_barrier(0);
  __builtin_amdgcn_s_barrier();

  const int colg = dt * 64 + wc * 16 + fr;
  for (int kk = 0; kk < 32; ++kk) {
    const int c = kk >> 2, buf = kk & 1;
    if ((kk & 3) == 0) {
      ushort* Sc = Mt + (size_t)(b * 8 + c) * 262144 + colg;
#pragma unroll
      for (int m = 0; m < 4; ++m)
#pragma unroll
        for (int r = 0; r < 4; ++r)
          Sc[(size_t)(et * 128 + wr * 64 + m * 16 + q4 + r) * 512] = bfbits(acc[m][r]);
    }
    if (kk + 1 < 32) {
      const int k0b = ((kk + 1) >> 2) * 512 + ((kk + 1) & 3) * 128;
      stage_half(Ab, 32768, k0b, smem + ((buf ^ 1) << 14), w, lane);
      stage_q64(Bb, 32768, k0b, smem + 32768 + ((buf ^ 1) << 13), tid);
    }
    const char* cA = smem + (buf << 14);
    const char* cB = smem + 32768 + (buf << 13);
    bf16x8 af[4][2], bg[2];
#pragma unroll
    for (int s = 0; s < 2; ++s) bg[s] = *frag_at(cB, wc * 16 + fr, s * 64 + foB);
#pragma unroll
    for (int m = 0; m < 4; ++m)
#pragma unroll
      for (int s = 0; s < 2; ++s)
        af[m][s] = *frag_at(cA, wr * 64 + m * 16 + fr, s * 64 + foB);
    __builtin_amdgcn_s_setprio(1);
#pragma unroll
    for (int m = 0; m < 4; ++m)
#pragma unroll
      for (int s = 0; s < 2; ++s)
        acc[m] = __builtin_amdgcn_mfma_f32_16x16x32_bf16(af[m][s], bg[s], acc[m], 0, 0, 0);
    __builtin_amdgcn_s_setprio(0);
    asm volatile("s_waitcnt vmcnt(0)" ::: "memory");
    __builtin_amdgcn_sched_barrier(0);
    __builtin_amdgcn_s_barrier();
  }
}

// ---- y uber-kernel: G(LDS) + den in-block + y = (Q St^T + G Vt^T)/den ----
__global__ __launch_bounds__(512, 2) void k8_y(const ushort* __restrict__ qb,
                                               const ushort* __restrict__ kkb,
                                               const ushort* __restrict__ St,
                                               const ushort* __restrict__ Vt,
                                               const float* __restrict__ zsumH,
                                               ushort* __restrict__ Y) {
  extern __shared__ char smem[];
  const int o = blockIdx.x;
  const int wg = (o & 7) * 32 + (o >> 3);
  const int bc = wg >> 2, rh = (wg >> 1) & 1, ch = wg & 1;
  const int b = bc >> 3, c = bc & 7;
  const int tid = threadIdx.x, w = tid >> 6, lane = tid & 63;
  const int wr = w >> 2, wc = w & 3, fr = lane & 15, q4 = (lane >> 4) << 2;
  char* sA = smem + 65536;
  char* sB = smem + 98304;
  const char* qptr = (const char*)(qb + (size_t)bc * 131072 + (size_t)rh * 65536);

  ACC4_INIT
  core8h(qptr, 1024, (const char*)(kkb + (size_t)bc * 131072), 1024, 8, sA, sB, acc, w, lane);

  float rs[4][4];
#pragma unroll
  for (int m = 0; m < 4; ++m)
#pragma unroll
    for (int r = 0; r < 4; ++r) rs[m][r] = 0.f;
#pragma unroll
  for (int m = 0; m < 4; ++m)
#pragma unroll
    for (int n = 0; n < 4; ++n)
#pragma unroll
      for (int r = 0; r < 4; ++r) {
        int rowL = wr * 64 + m * 16 + q4 + r;
        int col = wc * 64 + n * 16 + fr;
        float v = (col <= rh * 128 + rowL) ? acc[m][n][r] : 0.f;
        rs[m][r] += v;
        int byte = (rowL << 7) + ((col & 63) << 1);
        byte ^= (rowL & 7) << 4;
        *(__bf16*)(smem + (wc << 14) + byte) = (__bf16)v;
      }
#pragma unroll
  for (int m = 0; m < 4; ++m)
#pragma unroll
    for (int r = 0; r < 4; ++r) {
      rs[m][r] += __shfl_xor(rs[m][r], 1, 64);
      rs[m][r] += __shfl_xor(rs[m][r], 2, 64);
      rs[m][r] += __shfl_xor(rs[m][r], 4, 64);
      rs[m][r] += __shfl_xor(rs[m][r], 8, 64);
    }
  float* red = (float*)sA;
  float* zpl = red + 512;
  float* dend = zpl + 512;
  if (fr == 0) {
#pragma unroll
    for (int m = 0; m < 4; ++m)
#pragma unroll
      for (int r = 0; r < 4; ++r) red[wc * 128 + wr * 64 + m * 16 + q4 + r] = rs[m][r];
  }
  {
    float a = 0.f;
    for (int cp = 0; cp < c; ++cp)
      a += zsumH[(size_t)((b * 8 + cp) * 2) * 512 + tid] +
           zsumH[(size_t)((b * 8 + cp) * 2 + 1) * 512 + tid];
    zpl[tid] = a;
  }
  __syncthreads();
  {
    int rl = tid >> 2, quarter = tid & 3;
    int trow = bc * 256 + rh * 128 + rl;
    const ushort* qrow = qb + (size_t)trow * 512 + quarter * 128;
    const float* zq = zpl + quarter * 128;
    float s = 0.f;
    for (int j = 0; j < 128; j += 8) {
      ushort8 qv = *(const ushort8*)&qrow[j];
#pragma unroll
      for (int u = 0; u < 8; ++u) s = fmaf(bff(qv[u]), zq[j + u], s);
    }
    s += __shfl_xor(s, 1, 64);
    s += __shfl_xor(s, 2, 64);
    if (quarter == 0)
      dend[rl] = s + red[rl] + red[128 + rl] + red[256 + rl] + red[384 + rl] + 1e-6f;
  }
  __syncthreads();
  float dinv[4][4];
#pragma unroll
  for (int m = 0; m < 4; ++m)
#pragma unroll
    for (int r = 0; r < 4; ++r) dinv[m][r] = 1.f / dend[wr * 64 + m * 16 + q4 + r];
  __syncthreads();

  ACC4_ZERO
  core8h(qptr, 1024, (const char*)(St + (size_t)bc * 262144 + (size_t)ch * 131072), 1024, 8,
         sA, sB, acc, w, lane);
  core8h_ldsA(smem, (const char*)(Vt + (size_t)ch * 256 * 16384 + (size_t)bc * 256), 32768,
              rh ? 4 : 2, sB, acc, w, lane);

#pragma unroll
  for (int m = 0; m < 4; ++m)
#pragma unroll
    for (int n = 0; n < 4; ++n)
#pragma unroll
      for (int r = 0; r < 4; ++r) {
        size_t row = (size_t)bc * 256 + rh * 128 + wr * 64 + m * 16 + q4 + r;
        size_t col = (size_t)ch * 256 + wc * 64 + n * 16 + fr;
        Y[row * 512 + col] = bfbits(acc[m][n][r] * dinv[m][r]);
      }
}

// ---- out = Y WpT^T (fp32) : 256 blocks, core8h ----
__global__ __launch_bounds__(512, 2) void k8_out(const ushort* __restrict__ Y,
                                                 const ushort* __restrict__ wt,
                                                 float* __restrict__ out) {
  extern __shared__ char smem[];
  const int o = blockIdx.x;
  const int wg = (o & 7) * 32 + (o >> 3);
  const int mt = wg >> 1, ct = wg & 1;
  const int tid = threadIdx.x, w = tid >> 6, lane = tid & 63;
  ACC4_INIT
  core8h((const char*)(Y + (size_t)mt * 65536), 1024,
         (const char*)(wt + 786432 + (size_t)ct * 131072), 1024, 8,
         smem, smem + 32768, acc, w, lane);
  const int wr = w >> 2, wc = w & 3, fr = lane & 15, q4 = (lane >> 4) << 2;
  const size_t row0 = (size_t)mt * 128 + wr * 64;
  const size_t col0 = (size_t)ct * 256 + wc * 64;
#pragma unroll
  for (int m = 0; m < 4; ++m)
#pragma unroll
    for (int n = 0; n < 4; ++n)
#pragma unroll
      for (int r = 0; r < 4; ++r)
        out[(row0 + m * 16 + q4 + r) * 512 + col0 + n * 16 + fr] = acc[m][n][r];
}

// ---- W -> W^T bf16 only (256 blocks) ----
__global__ __launch_bounds__(256) void k_pre(const float* __restrict__ Wq,
                                             const float* __restrict__ Wk,
                                             const float* __restrict__ Wv,
                                             const float* __restrict__ Wp,
                                             ushort* __restrict__ wt) {
  __shared__ float tile[64][65];
  const int g = blockIdx.x;
  const int bz = g >> 6, rem = g & 63, bxw = rem >> 3, byw = rem & 7;
  const float* src = bz == 0 ? Wq : bz == 1 ? Wk : bz == 2 ? Wv : Wp;
  ushort* dst = wt + (size_t)bz * 262144;
  const int d0 = bxw * 64, n0 = byw * 64;
  const int tr = threadIdx.x >> 4, tc = (threadIdx.x & 15) << 2;
#pragma unroll
  for (int it = 0; it < 4; ++it) {
    float4 f = *(const float4*)&src[(size_t)(d0 + it * 16 + tr) * 512 + n0 + tc];
    tile[it * 16 + tr][tc + 0] = f.x;
    tile[it * 16 + tr][tc + 1] = f.y;
    tile[it * 16 + tr][tc + 2] = f.z;
    tile[it * 16 + tr][tc + 3] = f.w;
  }
  __syncthreads();
#pragma unroll
  for (int it = 0; it < 4; ++it) {
    int n = it * 16 + tr;
    ushort4 ov;
    ov.x = bfbits(tile[tc + 0][n]);
    ov.y = bfbits(tile[tc + 1][n]);
    ov.z = bfbits(tile[tc + 2][n]);
    ov.w = bfbits(tile[tc + 3][n]);
    *(ushort4*)&dst[(size_t)(n0 + n) * 512 + d0 + tc] = ov;
  }
}

extern "C" void kernel_launch(void* const* d_in, const int* in_sizes, int n_in,
                              void* d_out, int out_size, void* d_ws, size_t ws_size,
                              hipStream_t stream) {
  const float* x  = (const float*)d_in[0];
  const float* Wq = (const float*)d_in[1];
  const float* Wk = (const float*)d_in[2];
  const float* Wv = (const float*)d_in[3];
  const float* Wp = (const float*)d_in[4];
  float* out = (float*)d_out;
  char* ws8 = (char*)d_ws;
  if (ws_size < WS_NEED) return;

  ushort* wt  = (ushort*)(ws8 + OFF_WT);
  ushort* qb  = (ushort*)(ws8 + OFF_Q);
  ushort* kkb = (ushort*)(ws8 + OFF_KK);
  ushort* Kt  = (ushort*)(ws8 + OFF_KT);
  ushort* Vt  = (ushort*)(ws8 + OFF_VT);
  ushort* Mt  = (ushort*)(ws8 + OFF_MT);
  ushort* Y   = (ushort*)(ws8 + OFF_Y);
  float*  zpH = (float*)(ws8 + OFF_ZP);

  constexpr int SMEM_QKVT = 131072, SMEM_H = 98304, SMEM_Y = 163840;
  hipFuncSetAttribute((const void*)k8_qkvt, hipFuncAttributeMaxDynamicSharedMemorySize, SMEM_QKVT);
  hipFuncSetAttribute((const void*)k8_y,    hipFuncAttributeMaxDynamicSharedMemorySize, SMEM_Y);
  hipFuncSetAttribute((const void*)k8_out,  hipFuncAttributeMaxDynamicSharedMemorySize, SMEM_H);

  k_pre<<<256, 256, 0, stream>>>(Wq, Wk, Wv, Wp, wt);
  k8_qkvt<<<512, 512, SMEM_QKVT, stream>>>(x, wt, qb, kkb, Kt, Vt, zpH);
  k8_mtst<<<256, 512, 0, stream>>>(Kt, Vt, Mt);
  k8_y<<<256, 512, SMEM_Y, stream>>>(qb, kkb, Mt, Vt, zpH, Y);
  k8_out<<<256, 512, SMEM_H, stream>>>(Y, wt, out);
}